// Round 2
// baseline (1275.568 us; speedup 1.0000x reference)
//
#include <hip/hip_runtime.h>
#include <math.h>

// RegionProposalNetwork on MI355X (gfx950).
// Inputs are float32 (as setup_inputs declares) -> const float*.
// Output buffer float32: (loss[1], fm[2560000], proposals[128], pos_index[32], gt_cls[32]).
// All math f32. Selection path (anchors/IoU/top-k) uses fp contract(off) so it
// tracks the np f32 reference's ordering as closely as possible.

#define CAP 4096

// ---------------- workspace layout (float offsets), total ~45.5 MB ----------------
#define OFF_FM1     0          // 10,240,000 (64x400x400) -- dead after conv2
#define OFF_H       0          //  2,560,000 (rpn hidden, reuses fm1 region)
#define OFF_CPART   2560000    //    720,000 (4*18*10000)
#define OFF_RPART   3280000    //  1,440,000 (4*36*10000)
#define OFF_WT1     10240000   //      9,408 [147][64]
#define OFF_WT2     10249408   //    147,456 [576][256]
#define OFF_WTR     10396864   //    589,824 [2304][256]
#define OFF_AARG    10986688   //     90,000 (int)
#define OFF_PSC     11076688   //     90,000
#define OFF_NEGF    11166688   //     90,000 (int)
#define OFF_GTMAX   11256688   //     64 (uint) + 1 counter (padded 80)
#define OFF_PIDX    11256768   //     32 (int)
#define OFF_NIDX    11256800   //     32 (int)
#define OFF_WTC     11256832   //      4,608 [256][18]
#define OFF_WTG     11261440   //      9,216 [256][36]
#define OFF_CANDS   11270656   //      4,096
#define OFF_CANDI   11274752   //      4,096 (int)

// ---------------- selection-path exact math ----------------
__device__ __forceinline__ void anchor_box(int i, float& x0, float& y0,
                                           float& x1, float& y1, float& area) {
#pragma clang fp contract(off)
    const float sizes[3]  = {128.f, 256.f, 512.f};
    const float ratios[3] = {0.5f, 1.f, 2.f};
    int a = i % 9;
    int q = i / 9;
    int iy = q % 100;
    int ix = q / 100;
    int s = a / 3, r = a % 3;
    float sq = sqrtf(ratios[r]);
    float w = sizes[s] * sq;
    float h = sizes[s] / sq;
    float cx = ((float)ix + 0.5f) * 16.0f;
    float cy = ((float)iy + 0.5f) * 16.0f;
    x0 = cx - w * 0.5f;
    y0 = cy - h * 0.5f;
    x1 = x0 + w;
    y1 = y0 + h;
    area = (x1 - x0) * (y1 - y0);
}

__device__ __forceinline__ float iou_one(float ax0, float ay0, float ax1, float ay1, float aa,
                                         float bx0, float by0, float bx1, float by1, float ab) {
#pragma clang fp contract(off)
    float ltx = fmaxf(ax0, bx0), lty = fmaxf(ay0, by0);
    float rbx = fminf(ax1, bx1), rby = fminf(ay1, by1);
    float iw = fmaxf(rbx - ltx, 0.0f);
    float ih = fmaxf(rby - lty, 0.0f);
    float inter = iw * ih;
    return inter / ((aa + ab) - inter);
}

// ---------------- small utility kernels ----------------
__global__ void init_kernel(unsigned int* p) {
    int t = threadIdx.x;
    if (t < 65) p[t] = 0u;   // gtmax[64] + cand counter
}

__global__ void transpose_w(const float* __restrict__ src,
                            float* __restrict__ dst, int C, int K) {
    int idx = blockIdx.x * 256 + threadIdx.x;
    if (idx < C * K) {
        int c = idx / K;
        int k = idx - c * K;
        dst[k * C + c] = src[idx];
    }
}

// ---------------- conv1: 3->64, 7x7, s4, p3, 1600^2 -> 400^2 ----------------
__global__ __launch_bounds__(256) void conv1_kernel(const float* __restrict__ img,
                                                    const float* __restrict__ wt,   // [147][64]
                                                    const float* __restrict__ bias,
                                                    float* __restrict__ out) {      // [64][400][400]
    __shared__ float sin_[3][67][68];
    int t = threadIdx.x;
    int ox0 = blockIdx.x * 16, oy0 = blockIdx.y * 16;
    int ix0 = ox0 * 4 - 3, iy0 = oy0 * 4 - 3;
    for (int idx = t; idx < 3 * 67 * 67; idx += 256) {
        int ic = idx / 4489;
        int r = idx - ic * 4489;
        int yy = r / 67, xx = r - yy * 67;
        int gy = iy0 + yy, gx = ix0 + xx;
        float v = 0.f;
        if (gy >= 0 && gy < 1600 && gx >= 0 && gx < 1600)
            v = img[(ic * 1600 + gy) * 1600 + gx];
        sin_[ic][yy][xx] = v;
    }
    __syncthreads();
    int cg = t & 3, pg = t >> 2;
    int c0 = cg * 16;
    int px = (pg & 7) * 2, py = (pg >> 3) * 2;
    float acc[4][16];
#pragma unroll
    for (int p = 0; p < 4; p++)
#pragma unroll
        for (int j = 0; j < 16; j++) acc[p][j] = 0.f;

    for (int ic = 0; ic < 3; ic++)
        for (int ky = 0; ky < 7; ky++)
#pragma unroll
            for (int kx = 0; kx < 7; kx++) {
                int k = (ic * 7 + ky) * 7 + kx;
                const float4* wp = (const float4*)(wt + k * 64 + c0);
                float4 wa = wp[0], wb = wp[1], wc4 = wp[2], wd = wp[3];
                float wv[16] = {wa.x, wa.y, wa.z, wa.w, wb.x, wb.y, wb.z, wb.w,
                                wc4.x, wc4.y, wc4.z, wc4.w, wd.x, wd.y, wd.z, wd.w};
                float iv[4];
                iv[0] = sin_[ic][py * 4 + ky][px * 4 + kx];
                iv[1] = sin_[ic][py * 4 + ky][px * 4 + 4 + kx];
                iv[2] = sin_[ic][py * 4 + 4 + ky][px * 4 + kx];
                iv[3] = sin_[ic][py * 4 + 4 + ky][px * 4 + 4 + kx];
#pragma unroll
                for (int p = 0; p < 4; p++)
#pragma unroll
                    for (int j = 0; j < 16; j++) acc[p][j] += iv[p] * wv[j];
            }
#pragma unroll
    for (int j = 0; j < 16; j++) {
        float b = bias[c0 + j];
#pragma unroll
        for (int p = 0; p < 4; p++) {
            int oy = oy0 + py + (p >> 1), ox = ox0 + px + (p & 1);
            out[((c0 + j) * 400 + oy) * 400 + ox] = fmaxf(acc[p][j] + b, 0.f);
        }
    }
}

// ---------------- conv2: 64->256, 3x3, s4, p1, 400^2 -> 100^2 ----------------
__global__ __launch_bounds__(256) void conv2_kernel(const float* __restrict__ fin,  // [64][400][400]
                                                    const float* __restrict__ wt,   // [576][256]
                                                    const float* __restrict__ bias,
                                                    float* __restrict__ fmout) {    // d_out + 1 (f32)
    __shared__ float sin_[64][15][16];
    int t = threadIdx.x;
    int ox0 = blockIdx.x * 4, oy0 = blockIdx.y * 4;
    int ix0 = ox0 * 4 - 1, iy0 = oy0 * 4 - 1;
    for (int idx = t; idx < 64 * 225; idx += 256) {
        int ic = idx / 225;
        int r = idx - ic * 225;
        int yy = r / 15, xx = r - yy * 15;
        int gy = iy0 + yy, gx = ix0 + xx;
        float v = 0.f;
        if (gy >= 0 && gy < 400 && gx >= 0 && gx < 400)
            v = fin[(ic * 400 + gy) * 400 + gx];
        sin_[ic][yy][xx] = v;
    }
    __syncthreads();
    int cg = t & 15, pg = t >> 4;
    int c0 = cg * 16;
    int px = pg & 3, py = pg >> 2;
    float acc[16];
#pragma unroll
    for (int j = 0; j < 16; j++) acc[j] = 0.f;

    for (int ic = 0; ic < 64; ic++)
#pragma unroll
        for (int ky = 0; ky < 3; ky++)
#pragma unroll
            for (int kx = 0; kx < 3; kx++) {
                int k = (ic * 3 + ky) * 3 + kx;
                const float4* wp = (const float4*)(wt + k * 256 + c0);
                float4 wa = wp[0], wb = wp[1], wc4 = wp[2], wd = wp[3];
                float wv[16] = {wa.x, wa.y, wa.z, wa.w, wb.x, wb.y, wb.z, wb.w,
                                wc4.x, wc4.y, wc4.z, wc4.w, wd.x, wd.y, wd.z, wd.w};
                float v = sin_[ic][py * 4 + ky][px * 4 + kx];
#pragma unroll
                for (int j = 0; j < 16; j++) acc[j] += v * wv[j];
            }
    int oy = oy0 + py, ox = ox0 + px;
#pragma unroll
    for (int j = 0; j < 16; j++) {
        float v = fmaxf(acc[j] + bias[c0 + j], 0.f);
        fmout[(c0 + j) * 10000 + oy * 100 + ox] = v;
    }
}

// ---------------- conv3 (rpn): 256->256, 3x3, s1, p1, 100^2 ----------------
__global__ __launch_bounds__(256) void conv3_kernel(const float* __restrict__ fin,  // fm (d_out+1)
                                                    const float* __restrict__ wt,   // [2304][256]
                                                    const float* __restrict__ bias,
                                                    float* __restrict__ out) {      // h [256][100][100]
    __shared__ float sin_[32][18][18];
    int t = threadIdx.x;
    int ox0 = blockIdx.x * 16, oy0 = blockIdx.y * 16;
    int c0 = blockIdx.z * 32;
    int px = t & 15, py = t >> 4;
    float acc[32];
#pragma unroll
    for (int j = 0; j < 32; j++) acc[j] = 0.f;

    for (int ch = 0; ch < 8; ch++) {
        __syncthreads();
        for (int idx = t; idx < 32 * 324; idx += 256) {
            int ic = idx / 324;
            int r = idx - ic * 324;
            int yy = r / 18, xx = r - yy * 18;
            int gy = oy0 - 1 + yy, gx = ox0 - 1 + xx;
            float v = 0.f;
            if (gy >= 0 && gy < 100 && gx >= 0 && gx < 100)
                v = fin[((ch * 32 + ic) * 100 + gy) * 100 + gx];
            sin_[ic][yy][xx] = v;
        }
        __syncthreads();
        for (int ic = 0; ic < 32; ic++)
#pragma unroll
            for (int ky = 0; ky < 3; ky++)
#pragma unroll
                for (int kx = 0; kx < 3; kx++) {
                    float v = sin_[ic][py + ky][px + kx];
                    int k = ((ch * 32 + ic) * 3 + ky) * 3 + kx;
                    const float* wp = wt + k * 256 + c0;   // wave-uniform -> s_load
#pragma unroll
                    for (int j = 0; j < 32; j++) acc[j] += v * wp[j];
                }
    }
    int oy = oy0 + py, ox = ox0 + px;
    if (oy < 100 && ox < 100) {
#pragma unroll
        for (int j = 0; j < 32; j++)
            out[(c0 + j) * 10000 + oy * 100 + ox] = fmaxf(acc[j] + bias[c0 + j], 0.f);
    }
}

// ---------------- 1x1 heads: partial sums over 64-channel chunks ----------------
__global__ __launch_bounds__(256) void head_kernel(const float* __restrict__ hbuf,
                                                   const float* __restrict__ wtc,  // [256][18]
                                                   const float* __restrict__ wtg,  // [256][36]
                                                   float* __restrict__ cpart,      // [4][18][10000]
                                                   float* __restrict__ rpart) {    // [4][36][10000]
    int p = blockIdx.x * 256 + threadIdx.x;
    int ch = blockIdx.y;
    int ic0 = ch * 64;
    if (p >= 10000) return;
    float acc[54];
#pragma unroll
    for (int j = 0; j < 54; j++) acc[j] = 0.f;
    for (int ic = 0; ic < 64; ic++) {
        float v = hbuf[(ic0 + ic) * 10000 + p];
        const float* wc_ = wtc + (ic0 + ic) * 18;
#pragma unroll
        for (int j = 0; j < 18; j++) acc[j] += v * wc_[j];
        const float* wg_ = wtg + (ic0 + ic) * 36;
#pragma unroll
        for (int j = 0; j < 36; j++) acc[18 + j] += v * wg_[j];
    }
    for (int j = 0; j < 18; j++) cpart[(ch * 18 + j) * 10000 + p] = acc[j];
    for (int j = 0; j < 36; j++) rpart[(ch * 36 + j) * 10000 + p] = acc[18 + j];
}

// ---------------- IoU pass 1: anc argmax + per-gt max ----------------
__global__ __launch_bounds__(256) void iou_pass1(const float* __restrict__ gt,
                                                 int* __restrict__ aarg,
                                                 unsigned int* __restrict__ gtmax) {
    __shared__ float sg[64][4];
    __shared__ float sarea[64];
    __shared__ unsigned int smax[64];
    int t = threadIdx.x;
    if (t < 64) {
#pragma clang fp contract(off)
        float b0 = gt[t * 4 + 0], b1 = gt[t * 4 + 1];
        float b2 = gt[t * 4 + 2], b3 = gt[t * 4 + 3];
        sg[t][0] = b0; sg[t][1] = b1; sg[t][2] = b2; sg[t][3] = b3;
        sarea[t] = (b2 - b0) * (b3 - b1);
        smax[t] = 0u;
    }
    __syncthreads();
    int i = blockIdx.x * 256 + t;
    int iq = min(i, 89999);              // keep all 64 lanes active for the shuffles
    float x0, y0, x1, y1, aa;
    anchor_box(iq, x0, y0, x1, y1, aa);
    float best = -1.f;
    int bestj = 0;
    for (int j = 0; j < 64; j++) {
        float v = iou_one(x0, y0, x1, y1, aa, sg[j][0], sg[j][1], sg[j][2], sg[j][3], sarea[j]);
        if (v > best) { best = v; bestj = j; }
        float vm = v;                     // wave-reduce max -> 1 LDS atomic per wave
#pragma unroll
        for (int off = 32; off > 0; off >>= 1) vm = fmaxf(vm, __shfl_xor(vm, off));
        if ((t & 63) == 0) atomicMax(&smax[j], __float_as_uint(vm));
    }
    if (i < 90000) aarg[i] = bestj;
    __syncthreads();
    if (t < 64) atomicMax(&gtmax[t], smax[t]);
}

// ---------------- IoU pass 2: labels + pos compaction ----------------
__global__ __launch_bounds__(256) void iou_pass2(const float* __restrict__ gt,
                                                 const unsigned int* __restrict__ gtmax,
                                                 float* __restrict__ psc,
                                                 int* __restrict__ negf,
                                                 float* __restrict__ cand_s,
                                                 int* __restrict__ cand_i,
                                                 unsigned int* __restrict__ cnt) {
    __shared__ float sg[64][4];
    __shared__ float sarea[64];
    __shared__ float sgm[64];
    int t = threadIdx.x;
    if (t < 64) {
#pragma clang fp contract(off)
        float b0 = gt[t * 4 + 0], b1 = gt[t * 4 + 1];
        float b2 = gt[t * 4 + 2], b3 = gt[t * 4 + 3];
        sg[t][0] = b0; sg[t][1] = b1; sg[t][2] = b2; sg[t][3] = b3;
        sarea[t] = (b2 - b0) * (b3 - b1);
        sgm[t] = __uint_as_float(gtmax[t]);
    }
    __syncthreads();
    int i = blockIdx.x * 256 + t;
    if (i >= 90000) return;
    float x0, y0, x1, y1, aa;
    anchor_box(i, x0, y0, x1, y1, aa);
    float best = -1.f;
    bool isbest = false;
    for (int j = 0; j < 64; j++) {
        float v = iou_one(x0, y0, x1, y1, aa, sg[j][0], sg[j][1], sg[j][2], sg[j][3], sarea[j]);
        if (v > best) best = v;
        if (v == sgm[j]) isbest = true;   // exact equality, identical f32 code path as pass 1
    }
    float label = -1.f;
    if (best < 0.2f) label = 0.f;
    if (isbest) label = 1.f;
    if (best > 0.7f) label = 1.f;
    psc[i] = (label == 1.f) ? best : -1.0f;
    negf[i] = (label == 0.f) ? 1 : 0;
    if (label == 1.f) {
        unsigned int p = atomicAdd(cnt, 1u);
        if (p < CAP) { cand_s[p] = best; cand_i[p] = i; }
    }
}

// ---------------- top-k selection (jax.lax.top_k semantics) ----------------
__global__ __launch_bounds__(256) void select_kernel(const float* __restrict__ psc,
                                                     const int* __restrict__ negf,
                                                     const float* __restrict__ cand_s,
                                                     const int* __restrict__ cand_i,
                                                     const unsigned int* __restrict__ cnt,
                                                     int* __restrict__ pidx,
                                                     int* __restrict__ nidx) {
    __shared__ float cs[CAP + 32];
    __shared__ int ci[CAP + 32];
    __shared__ int spart[256];
    __shared__ int sfound;
    __shared__ int sfill[32];
    __shared__ float rs[256];
    __shared__ int ri[256];
    __shared__ int rslot[256];
    int t = threadIdx.x;
    int ncand = min((int)*cnt, CAP);
    for (int c = t; c < ncand; c += 256) { cs[c] = cand_s[c]; ci[c] = cand_i[c]; }
    if (t == 0) sfound = 0;
    __syncthreads();

    int nfill = 0;
    if (ncand < 32) {
        // first (32-ncand worth of) indices with label != 1, index order (top_k tie fill, val -1)
        for (int base = 0; base < 90000; base += 2048) {
            if (sfound >= 32) break;
            int f[8];
            int c8 = 0;
#pragma unroll
            for (int u = 0; u < 8; u++) {
                int i = base + t * 8 + u;
                int fl = (i < 90000 && psc[i] < 0.f) ? 1 : 0;
                f[u] = fl;
                c8 += fl;
            }
            spart[t] = c8;
            __syncthreads();
            for (int off = 1; off < 256; off <<= 1) {
                int v = (t >= off) ? spart[t - off] : 0;
                __syncthreads();
                spart[t] += v;
                __syncthreads();
            }
            int pref = sfound + spart[t] - c8;
            int total = spart[255];
#pragma unroll
            for (int u = 0; u < 8; u++) {
                if (f[u]) { if (pref < 32) sfill[pref] = base + t * 8 + u; pref++; }
            }
            __syncthreads();
            if (t == 0) sfound += total;
            __syncthreads();
        }
        nfill = min(sfound, 32);
        for (int k = t; k < nfill; k += 256) { cs[ncand + k] = -1.0f; ci[ncand + k] = sfill[k]; }
    }
    __syncthreads();
    int ntot = ncand + nfill;

    // 32 rounds of argmax with (score desc, index asc) comparator
    for (int s = 0; s < 32; s++) {
        float bs = -1e30f;
        int bi = 0x7fffffff;
        int bsl = -1;
        for (int c = t; c < ntot; c += 256) {
            float v = cs[c];
            int id = ci[c];
            if (v > bs || (v == bs && id < bi)) { bs = v; bi = id; bsl = c; }
        }
        rs[t] = bs; ri[t] = bi; rslot[t] = bsl;
        __syncthreads();
        for (int off = 128; off > 0; off >>= 1) {
            if (t < off) {
                if (rs[t + off] > rs[t] || (rs[t + off] == rs[t] && ri[t + off] < ri[t])) {
                    rs[t] = rs[t + off]; ri[t] = ri[t + off]; rslot[t] = rslot[t + off];
                }
            }
            __syncthreads();
        }
        if (t == 0) { pidx[s] = ri[0]; cs[rslot[0]] = -1e30f; }
        __syncthreads();
    }

    // negatives: first 32 indices with label == 0 (scores 1e6-idx are distinct, desc = idx asc)
    if (t == 0) sfound = 0;
    __syncthreads();
    for (int base = 0; base < 90000; base += 2048) {
        if (sfound >= 32) break;
        int f[8];
        int c8 = 0;
#pragma unroll
        for (int u = 0; u < 8; u++) {
            int i = base + t * 8 + u;
            int fl = (i < 90000 && negf[i] != 0) ? 1 : 0;
            f[u] = fl;
            c8 += fl;
        }
        spart[t] = c8;
        __syncthreads();
        for (int off = 1; off < 256; off <<= 1) {
            int v = (t >= off) ? spart[t - off] : 0;
            __syncthreads();
            spart[t] += v;
            __syncthreads();
        }
        int pref = sfound + spart[t] - c8;
        int total = spart[255];
#pragma unroll
        for (int u = 0; u < 8; u++) {
            if (f[u]) { if (pref < 32) nidx[pref] = base + t * 8 + u; pref++; }
        }
        __syncthreads();
        if (t == 0) sfound += total;
        __syncthreads();
    }
    __syncthreads();
    if (t == 0) {
        int nf = min(sfound, 32);
        for (int s = nf; s < 32; s++) nidx[s] = s;  // degenerate fallback (shouldn't happen)
    }
}

// ---------------- finalize: proposals, losses, index outputs ----------------
__global__ __launch_bounds__(64) void finalize_kernel(const float* __restrict__ cpart,
                                                      const float* __restrict__ rpart,
                                                      const float* __restrict__ bcls,
                                                      const float* __restrict__ breg,
                                                      const int* __restrict__ pidx,
                                                      const int* __restrict__ nidx,
                                                      const int* __restrict__ aarg,
                                                      const float* __restrict__ gt,
                                                      const int* __restrict__ gtc,
                                                      float* __restrict__ out) {
#pragma clang fp contract(off)
    const int PROP_OFF = 1 + 2560000;
    int t = threadIdx.x;  // 64 threads = 1 wave
    int n = (t < 32) ? pidx[t] : nidx[t - 32];
    int a = n % 9;
    int q = n / 9;
    int iy = q % 100;
    int ix = q / 100;
    int p = iy * 100 + ix;

    // logits
    float l0 = bcls[a * 2 + 0], l1 = bcls[a * 2 + 1];
    for (int c = 0; c < 4; c++) {
        l0 += cpart[(c * 18 + a * 2 + 0) * 10000 + p];
        l1 += cpart[(c * 18 + a * 2 + 1) * 10000 + p];
    }
    float m = fmaxf(l0, l1);
    float lse = m + logf(expf(l0 - m) + expf(l1 - m));
    float logp = ((t < 32) ? l1 : l0) - lse;
    float cls_sum = logp;
#pragma unroll
    for (int off = 32; off > 0; off >>= 1) cls_sum += __shfl_down(cls_sum, off);

    float reg_sum = 0.f;
    if (t < 32) {
        float offv[4];
#pragma unroll
        for (int k = 0; k < 4; k++) {
            float v = breg[a * 4 + k];
            for (int c = 0; c < 4; c++) v += rpart[(c * 36 + a * 4 + k) * 10000 + p];
            offv[k] = v;
        }
        float x0, y0, x1, y1, aa;
        anchor_box(n, x0, y0, x1, y1, aa);
        float w = x1 - x0, h = y1 - y0;
        float cx = x0 + 0.5f * w, cy = y0 + 0.5f * h;
        float ncx = cx + offv[0] * w, ncy = cy + offv[1] * h;
        float nw = w * expf(offv[2]), nh = h * expf(offv[3]);
        out[PROP_OFF + t * 4 + 0] = ncx - nw * 0.5f;
        out[PROP_OFF + t * 4 + 1] = ncy - nh * 0.5f;
        out[PROP_OFF + t * 4 + 2] = ncx + nw * 0.5f;
        out[PROP_OFF + t * 4 + 3] = ncy + nh * 0.5f;

        int j = aarg[n];
        float g0 = gt[j * 4 + 0], g1 = gt[j * 4 + 1];
        float g2 = gt[j * 4 + 2], g3 = gt[j * 4 + 3];
        float gw = g2 - g0, gh = g3 - g1;
        float gcx = g0 + 0.5f * gw, gcy = g1 + 0.5f * gh;
        float tg[4];
        tg[0] = (gcx - cx) / w;
        tg[1] = (gcy - cy) / h;
        tg[2] = logf(gw / w);
        tg[3] = logf(gh / h);
#pragma unroll
        for (int k = 0; k < 4; k++) {
            float d = tg[k] - offv[k];
            float ad = fabsf(d);
            reg_sum += (ad < 1.f) ? 0.5f * d * d : ad - 0.5f;
        }
        out[PROP_OFF + 128 + t] = (float)n;        // pos_index
        out[PROP_OFF + 160 + t] = (float)gtc[j];   // gt_cls_pos
    }
#pragma unroll
    for (int off = 32; off > 0; off >>= 1) reg_sum += __shfl_down(reg_sum, off);
    if (t == 0) {
        float cls_loss = -(cls_sum / 64.f);
        float reg_loss = reg_sum / 128.f;
        out[0] = cls_loss + 5.f * reg_loss;
    }
}

// ---------------- launch ----------------
extern "C" void kernel_launch(void* const* d_in, const int* in_sizes, int n_in,
                              void* d_out, int out_size, void* d_ws, size_t ws_size,
                              hipStream_t stream) {
    const float* img = (const float*)d_in[0];
    const float* gt  = (const float*)d_in[1];
    const int*   gtc = (const int*)d_in[2];
    const float* w1  = (const float*)d_in[3];
    const float* b1  = (const float*)d_in[4];
    const float* w2  = (const float*)d_in[5];
    const float* b2  = (const float*)d_in[6];
    const float* wr  = (const float*)d_in[7];
    const float* br  = (const float*)d_in[8];
    const float* wc  = (const float*)d_in[9];
    const float* bc  = (const float*)d_in[10];
    const float* wg  = (const float*)d_in[11];
    const float* bg  = (const float*)d_in[12];
    float* out = (float*)d_out;
    float* ws = (float*)d_ws;

    float* fm1   = ws + OFF_FM1;
    float* hbuf  = ws + OFF_H;
    float* cpart = ws + OFF_CPART;
    float* rpart = ws + OFF_RPART;
    float* wt1   = ws + OFF_WT1;
    float* wt2   = ws + OFF_WT2;
    float* wtr   = ws + OFF_WTR;
    float* wtc   = ws + OFF_WTC;
    float* wtg   = ws + OFF_WTG;
    int*   aarg  = (int*)(ws + OFF_AARG);
    float* psc   = ws + OFF_PSC;
    int*   negf  = (int*)(ws + OFF_NEGF);
    unsigned int* gtmax = (unsigned int*)(ws + OFF_GTMAX);
    unsigned int* cnt   = gtmax + 64;
    int*   pidx  = (int*)(ws + OFF_PIDX);
    int*   nidx  = (int*)(ws + OFF_NIDX);
    float* cands = ws + OFF_CANDS;
    int*   candi = (int*)(ws + OFF_CANDI);
    float* fm    = out + 1;   // fm lives directly in the output buffer (f32)

    init_kernel<<<dim3(1), dim3(128), 0, stream>>>(gtmax);
    transpose_w<<<dim3(37), dim3(256), 0, stream>>>(w1, wt1, 64, 147);
    transpose_w<<<dim3(576), dim3(256), 0, stream>>>(w2, wt2, 256, 576);
    transpose_w<<<dim3(2304), dim3(256), 0, stream>>>(wr, wtr, 256, 2304);
    transpose_w<<<dim3(18), dim3(256), 0, stream>>>(wc, wtc, 18, 256);
    transpose_w<<<dim3(36), dim3(256), 0, stream>>>(wg, wtg, 36, 256);

    conv1_kernel<<<dim3(25, 25), dim3(256), 0, stream>>>(img, wt1, b1, fm1);
    conv2_kernel<<<dim3(25, 25), dim3(256), 0, stream>>>(fm1, wt2, b2, fm);
    conv3_kernel<<<dim3(7, 7, 8), dim3(256), 0, stream>>>(fm, wtr, br, hbuf);
    head_kernel<<<dim3(40, 4), dim3(256), 0, stream>>>(hbuf, wtc, wtg, cpart, rpart);

    iou_pass1<<<dim3(352), dim3(256), 0, stream>>>(gt, aarg, gtmax);
    iou_pass2<<<dim3(352), dim3(256), 0, stream>>>(gt, gtmax, psc, negf, cands, candi, cnt);
    select_kernel<<<dim3(1), dim3(256), 0, stream>>>(psc, negf, cands, candi, cnt, pidx, nidx);
    finalize_kernel<<<dim3(1), dim3(64), 0, stream>>>(cpart, rpart, bc, bg, pidx, nidx,
                                                      aarg, gt, gtc, out);
}

// Round 3
// 510.830 us; speedup vs baseline: 2.4970x; 2.4970x over previous
//
#include <hip/hip_runtime.h>
#include <math.h>

// RegionProposalNetwork on MI355X (gfx950).
// Round 3: conv2/conv3 as bf16 MFMA implicit GEMMs over zero-padded transposed
// feature maps. Selection path (anchors/IoU/top-k) unchanged, exact f32.

#define CAP 4096

typedef __attribute__((ext_vector_type(8))) short bf16x8;
typedef __attribute__((ext_vector_type(4))) float f32x4;

// ---------------- workspace layout (float offsets), total ~37.5 MB ----------------
#define OFF_F1T     0          // 5,171,328 f = 402*402*64 bf16 (conv1 out, padded transposed)
#define OFF_HBUF    0          // 2,560,000 f (rpn hidden; overlays F1T which is dead by then)
#define OFF_FMT     5171328    // 1,331,712 f = 102*102*256 bf16 (fm, padded transposed)
#define OFF_CPART   6503040    //   720,000 (4*18*10000)
#define OFF_RPART   7223040    // 1,440,000 (4*36*10000)
#define OFF_WT1     8663040    //     9,408 [147][64] f32
#define OFF_W9_2    8672448    //    73,728 f = 9*256*64 bf16
#define OFF_W9_3    8746176    //   294,912 f = 9*256*256 bf16
#define OFF_WTC     9041088    //     4,608 [256][18] f32
#define OFF_WTG     9045696    //     9,216 [256][36] f32
#define OFF_AARG    9054912    //    90,000 (int)
#define OFF_PSC     9144912    //    90,000
#define OFF_NEGF    9234912    //    90,000 (int)
#define OFF_GTMAX   9324912    //    64 uint + counter (pad 80)
#define OFF_PIDX    9324992    //    32 (int)
#define OFF_NIDX    9325024    //    32 (int)
#define OFF_CANDS   9325056    //    4,096
#define OFF_CANDI   9329152    //    4,096 (int)
#define ZERO_F      6503040    // zero-fill [0, ZERO_F) floats: F1T + FMT regions

__device__ __forceinline__ unsigned short f2bf(float f) {   // RNE f32->bf16
    unsigned int u = __float_as_uint(f);
    u += 0x7fffu + ((u >> 16) & 1u);
    return (unsigned short)(u >> 16);
}

// ---------------- selection-path exact math ----------------
__device__ __forceinline__ void anchor_box(int i, float& x0, float& y0,
                                           float& x1, float& y1, float& area) {
#pragma clang fp contract(off)
    const float sizes[3]  = {128.f, 256.f, 512.f};
    const float ratios[3] = {0.5f, 1.f, 2.f};
    int a = i % 9;
    int q = i / 9;
    int iy = q % 100;
    int ix = q / 100;
    int s = a / 3, r = a % 3;
    float sq = sqrtf(ratios[r]);
    float w = sizes[s] * sq;
    float h = sizes[s] / sq;
    float cx = ((float)ix + 0.5f) * 16.0f;
    float cy = ((float)iy + 0.5f) * 16.0f;
    x0 = cx - w * 0.5f;
    y0 = cy - h * 0.5f;
    x1 = x0 + w;
    y1 = y0 + h;
    area = (x1 - x0) * (y1 - y0);
}

__device__ __forceinline__ float iou_one(float ax0, float ay0, float ax1, float ay1, float aa,
                                         float bx0, float by0, float bx1, float by1, float ab) {
#pragma clang fp contract(off)
    float ltx = fmaxf(ax0, bx0), lty = fmaxf(ay0, by0);
    float rbx = fminf(ax1, bx1), rby = fminf(ay1, by1);
    float iw = fmaxf(rbx - ltx, 0.0f);
    float ih = fmaxf(rby - lty, 0.0f);
    float inter = iw * ih;
    return inter / ((aa + ab) - inter);
}

// ---------------- small utility kernels ----------------
__global__ void init_kernel(unsigned int* p) {
    int t = threadIdx.x;
    if (t < 65) p[t] = 0u;   // gtmax[64] + cand counter
}

__global__ void zero_kernel(float4* p, int n4) {
    int i = blockIdx.x * 256 + threadIdx.x;
    if (i < n4) p[i] = make_float4(0.f, 0.f, 0.f, 0.f);
}

__global__ void transpose_w(const float* __restrict__ src,
                            float* __restrict__ dst, int C, int K) {
    int idx = blockIdx.x * 256 + threadIdx.x;
    if (idx < C * K) {
        int c = idx / K;
        int k = idx - c * K;
        dst[k * C + c] = src[idx];
    }
}

// repack [oc][ic][3][3] f32 -> [kk][oc][ic] bf16
__global__ void repack_w(const float* __restrict__ src, unsigned short* __restrict__ dst,
                         int IC) {
    int d = blockIdx.x * 256 + threadIdx.x;
    int tot = 9 * 256 * IC;
    if (d >= tot) return;
    int kk = d / (256 * IC);
    int rem = d - kk * 256 * IC;
    int oc = rem / IC;
    int ic = rem - oc * IC;
    dst[d] = f2bf(src[(oc * IC + ic) * 9 + kk]);
}

// ---------------- conv1: 3->64, 7x7, s4, p3, 1600^2 -> 400^2, f32 VALU ----------------
// writes transposed+padded bf16: f1t[(oy+1)*402 + ox+1][64]
__global__ __launch_bounds__(256) void conv1_kernel(const float* __restrict__ img,
                                                    const float* __restrict__ wt,   // [147][64]
                                                    const float* __restrict__ bias,
                                                    unsigned short* __restrict__ f1t) {
    __shared__ float sin_[3][67][68];
    int t = threadIdx.x;
    int ox0 = blockIdx.x * 16, oy0 = blockIdx.y * 16;
    int ix0 = ox0 * 4 - 3, iy0 = oy0 * 4 - 3;
    for (int idx = t; idx < 3 * 67 * 67; idx += 256) {
        int ic = idx / 4489;
        int r = idx - ic * 4489;
        int yy = r / 67, xx = r - yy * 67;
        int gy = iy0 + yy, gx = ix0 + xx;
        float v = 0.f;
        if (gy >= 0 && gy < 1600 && gx >= 0 && gx < 1600)
            v = img[(ic * 1600 + gy) * 1600 + gx];
        sin_[ic][yy][xx] = v;
    }
    __syncthreads();
    int cg = t & 3, pg = t >> 2;
    int c0 = cg * 16;
    int px = (pg & 7) * 2, py = (pg >> 3) * 2;
    float acc[4][16];
#pragma unroll
    for (int p = 0; p < 4; p++)
#pragma unroll
        for (int j = 0; j < 16; j++) acc[p][j] = 0.f;

    for (int ic = 0; ic < 3; ic++)
        for (int ky = 0; ky < 7; ky++)
#pragma unroll
            for (int kx = 0; kx < 7; kx++) {
                int k = (ic * 7 + ky) * 7 + kx;
                const float4* wp = (const float4*)(wt + k * 64 + c0);
                float4 wa = wp[0], wb = wp[1], wc4 = wp[2], wd = wp[3];
                float wv[16] = {wa.x, wa.y, wa.z, wa.w, wb.x, wb.y, wb.z, wb.w,
                                wc4.x, wc4.y, wc4.z, wc4.w, wd.x, wd.y, wd.z, wd.w};
                float iv[4];
                iv[0] = sin_[ic][py * 4 + ky][px * 4 + kx];
                iv[1] = sin_[ic][py * 4 + ky][px * 4 + 4 + kx];
                iv[2] = sin_[ic][py * 4 + 4 + ky][px * 4 + kx];
                iv[3] = sin_[ic][py * 4 + 4 + ky][px * 4 + 4 + kx];
#pragma unroll
                for (int p = 0; p < 4; p++)
#pragma unroll
                    for (int j = 0; j < 16; j++) acc[p][j] += iv[p] * wv[j];
            }
#pragma unroll
    for (int p = 0; p < 4; p++) {
        int oy = oy0 + py + (p >> 1), ox = ox0 + px + (p & 1);
        int row = (oy + 1) * 402 + ox + 1;
        unsigned short tmp[16];
#pragma unroll
        for (int j = 0; j < 16; j++)
            tmp[j] = f2bf(fmaxf(acc[p][j] + bias[c0 + j], 0.f));
        uint4* dst = (uint4*)(f1t + row * 64 + c0);
        dst[0] = ((uint4*)tmp)[0];
        dst[1] = ((uint4*)tmp)[1];
    }
}

// ---------------- implicit-GEMM conv via MFMA bf16 ----------------
// C[256 oc][10000 px] = sum over 9 passes, K=ICC per pass.
// Bt: padded transposed input [row][ICC] bf16, row = (S*y+ky)*RS + S*x+kx.
// A9: [pass][oc][ICC] bf16. Wave tile: 32 oc x 64 px. Block = 4 waves = 128 oc x 64 px.
template<int ICC, int RS, int S, bool WRT>
__global__ __launch_bounds__(256) void conv_gemm(const unsigned short* __restrict__ Bt,
                                                 const unsigned short* __restrict__ A9,
                                                 const float* __restrict__ bias,
                                                 float* __restrict__ outF,
                                                 unsigned short* __restrict__ outT) {
    int t = threadIdx.x;
    int wave = t >> 6, lane = t & 63;
    int quad = lane >> 4, l16 = lane & 15;
    int n0 = blockIdx.x * 64;
    int oc0 = blockIdx.y * 128 + wave * 32;
    int y[4], x[4];
#pragma unroll
    for (int j = 0; j < 4; j++) {
        int p = n0 + j * 16 + l16;
        int pe = min(p, 9999);              // clamp: OOB lanes compute discarded garbage
        y[j] = pe / 100;
        x[j] = pe - y[j] * 100;
    }
    f32x4 acc[2][4];
#pragma unroll
    for (int a = 0; a < 2; a++)
#pragma unroll
        for (int j = 0; j < 4; j++) acc[a][j] = (f32x4){0.f, 0.f, 0.f, 0.f};

    const int KCH = ICC / 32;
    for (int pass = 0; pass < 9; pass++) {
        int ky = pass / 3, kx = pass - (pass / 3) * 3;
        const bf16x8* aP0 = (const bf16x8*)(A9 + (size_t)pass * 256 * ICC + (oc0 + l16) * ICC + quad * 8);
        const bf16x8* aP1 = (const bf16x8*)(A9 + (size_t)pass * 256 * ICC + (oc0 + 16 + l16) * ICC + quad * 8);
        const bf16x8* bP[4];
#pragma unroll
        for (int j = 0; j < 4; j++) {
            int r = (S * y[j] + ky) * RS + S * x[j] + kx;
            bP[j] = (const bf16x8*)(Bt + (size_t)r * ICC + quad * 8);
        }
#pragma unroll
        for (int kc = 0; kc < KCH; kc++) {
            bf16x8 a0 = aP0[kc * 4];
            bf16x8 a1 = aP1[kc * 4];
#pragma unroll
            for (int j = 0; j < 4; j++) {
                bf16x8 b = bP[j][kc * 4];
                acc[0][j] = __builtin_amdgcn_mfma_f32_16x16x32_bf16(a0, b, acc[0][j], 0, 0, 0);
                acc[1][j] = __builtin_amdgcn_mfma_f32_16x16x32_bf16(a1, b, acc[1][j], 0, 0, 0);
            }
        }
    }
    // epilogue: D[m][n]: n = lane&15, m = quad*4+reg (per 16x16 tile)
#pragma unroll
    for (int a = 0; a < 2; a++) {
#pragma unroll
        for (int reg = 0; reg < 4; reg++) {
            int oc = oc0 + a * 16 + quad * 4 + reg;
            float bv = bias[oc];
#pragma unroll
            for (int j = 0; j < 4; j++) {
                int p = n0 + j * 16 + l16;
                if (p < 10000) {
                    float v = fmaxf(acc[a][j][reg] + bv, 0.f);
                    outF[oc * 10000 + p] = v;
                    if (WRT) {
                        int yy = p / 100, xx = p - (p / 100) * 100;
                        int r = (yy + 1) * 102 + xx + 1;
                        outT[r * 256 + oc] = f2bf(v);
                    }
                }
            }
        }
    }
}

// ---------------- 1x1 heads: partial sums over 64-channel chunks ----------------
__global__ __launch_bounds__(256) void head_kernel(const float* __restrict__ hbuf,
                                                   const float* __restrict__ wtc,  // [256][18]
                                                   const float* __restrict__ wtg,  // [256][36]
                                                   float* __restrict__ cpart,      // [4][18][10000]
                                                   float* __restrict__ rpart) {    // [4][36][10000]
    int p = blockIdx.x * 256 + threadIdx.x;
    int ch = blockIdx.y;
    int ic0 = ch * 64;
    if (p >= 10000) return;
    float acc[54];
#pragma unroll
    for (int j = 0; j < 54; j++) acc[j] = 0.f;
    for (int ic = 0; ic < 64; ic++) {
        float v = hbuf[(ic0 + ic) * 10000 + p];
        const float* wc_ = wtc + (ic0 + ic) * 18;
#pragma unroll
        for (int j = 0; j < 18; j++) acc[j] += v * wc_[j];
        const float* wg_ = wtg + (ic0 + ic) * 36;
#pragma unroll
        for (int j = 0; j < 36; j++) acc[18 + j] += v * wg_[j];
    }
    for (int j = 0; j < 18; j++) cpart[(ch * 18 + j) * 10000 + p] = acc[j];
    for (int j = 0; j < 36; j++) rpart[(ch * 36 + j) * 10000 + p] = acc[18 + j];
}

// ---------------- IoU pass 1: anc argmax + per-gt max ----------------
__global__ __launch_bounds__(256) void iou_pass1(const float* __restrict__ gt,
                                                 int* __restrict__ aarg,
                                                 unsigned int* __restrict__ gtmax) {
    __shared__ float sg[64][4];
    __shared__ float sarea[64];
    __shared__ unsigned int smax[64];
    int t = threadIdx.x;
    if (t < 64) {
#pragma clang fp contract(off)
        float b0 = gt[t * 4 + 0], b1 = gt[t * 4 + 1];
        float b2 = gt[t * 4 + 2], b3 = gt[t * 4 + 3];
        sg[t][0] = b0; sg[t][1] = b1; sg[t][2] = b2; sg[t][3] = b3;
        sarea[t] = (b2 - b0) * (b3 - b1);
        smax[t] = 0u;
    }
    __syncthreads();
    int i = blockIdx.x * 256 + t;
    int iq = min(i, 89999);              // keep all 64 lanes active for the shuffles
    float x0, y0, x1, y1, aa;
    anchor_box(iq, x0, y0, x1, y1, aa);
    float best = -1.f;
    int bestj = 0;
    for (int j = 0; j < 64; j++) {
        float v = iou_one(x0, y0, x1, y1, aa, sg[j][0], sg[j][1], sg[j][2], sg[j][3], sarea[j]);
        if (v > best) { best = v; bestj = j; }
        float vm = v;                     // wave-reduce max -> 1 LDS atomic per wave
#pragma unroll
        for (int off = 32; off > 0; off >>= 1) vm = fmaxf(vm, __shfl_xor(vm, off));
        if ((t & 63) == 0) atomicMax(&smax[j], __float_as_uint(vm));
    }
    if (i < 90000) aarg[i] = bestj;
    __syncthreads();
    if (t < 64) atomicMax(&gtmax[t], smax[t]);
}

// ---------------- IoU pass 2: labels + pos compaction ----------------
__global__ __launch_bounds__(256) void iou_pass2(const float* __restrict__ gt,
                                                 const unsigned int* __restrict__ gtmax,
                                                 float* __restrict__ psc,
                                                 int* __restrict__ negf,
                                                 float* __restrict__ cand_s,
                                                 int* __restrict__ cand_i,
                                                 unsigned int* __restrict__ cnt) {
    __shared__ float sg[64][4];
    __shared__ float sarea[64];
    __shared__ float sgm[64];
    int t = threadIdx.x;
    if (t < 64) {
#pragma clang fp contract(off)
        float b0 = gt[t * 4 + 0], b1 = gt[t * 4 + 1];
        float b2 = gt[t * 4 + 2], b3 = gt[t * 4 + 3];
        sg[t][0] = b0; sg[t][1] = b1; sg[t][2] = b2; sg[t][3] = b3;
        sarea[t] = (b2 - b0) * (b3 - b1);
        sgm[t] = __uint_as_float(gtmax[t]);
    }
    __syncthreads();
    int i = blockIdx.x * 256 + t;
    if (i >= 90000) return;
    float x0, y0, x1, y1, aa;
    anchor_box(i, x0, y0, x1, y1, aa);
    float best = -1.f;
    bool isbest = false;
    for (int j = 0; j < 64; j++) {
        float v = iou_one(x0, y0, x1, y1, aa, sg[j][0], sg[j][1], sg[j][2], sg[j][3], sarea[j]);
        if (v > best) best = v;
        if (v == sgm[j]) isbest = true;   // exact equality, identical f32 code path as pass 1
    }
    float label = -1.f;
    if (best < 0.2f) label = 0.f;
    if (isbest) label = 1.f;
    if (best > 0.7f) label = 1.f;
    psc[i] = (label == 1.f) ? best : -1.0f;
    negf[i] = (label == 0.f) ? 1 : 0;
    if (label == 1.f) {
        unsigned int p = atomicAdd(cnt, 1u);
        if (p < CAP) { cand_s[p] = best; cand_i[p] = i; }
    }
}

// ---------------- top-k selection (jax.lax.top_k semantics) ----------------
__global__ __launch_bounds__(256) void select_kernel(const float* __restrict__ psc,
                                                     const int* __restrict__ negf,
                                                     const float* __restrict__ cand_s,
                                                     const int* __restrict__ cand_i,
                                                     const unsigned int* __restrict__ cnt,
                                                     int* __restrict__ pidx,
                                                     int* __restrict__ nidx) {
    __shared__ float cs[CAP + 32];
    __shared__ int ci[CAP + 32];
    __shared__ int spart[256];
    __shared__ int sfound;
    __shared__ int sfill[32];
    __shared__ float rs[256];
    __shared__ int ri[256];
    __shared__ int rslot[256];
    int t = threadIdx.x;
    int ncand = min((int)*cnt, CAP);
    for (int c = t; c < ncand; c += 256) { cs[c] = cand_s[c]; ci[c] = cand_i[c]; }
    if (t == 0) sfound = 0;
    __syncthreads();

    int nfill = 0;
    if (ncand < 32) {
        for (int base = 0; base < 90000; base += 2048) {
            if (sfound >= 32) break;
            int f[8];
            int c8 = 0;
#pragma unroll
            for (int u = 0; u < 8; u++) {
                int i = base + t * 8 + u;
                int fl = (i < 90000 && psc[i] < 0.f) ? 1 : 0;
                f[u] = fl;
                c8 += fl;
            }
            spart[t] = c8;
            __syncthreads();
            for (int off = 1; off < 256; off <<= 1) {
                int v = (t >= off) ? spart[t - off] : 0;
                __syncthreads();
                spart[t] += v;
                __syncthreads();
            }
            int pref = sfound + spart[t] - c8;
            int total = spart[255];
#pragma unroll
            for (int u = 0; u < 8; u++) {
                if (f[u]) { if (pref < 32) sfill[pref] = base + t * 8 + u; pref++; }
            }
            __syncthreads();
            if (t == 0) sfound += total;
            __syncthreads();
        }
        nfill = min(sfound, 32);
        for (int k = t; k < nfill; k += 256) { cs[ncand + k] = -1.0f; ci[ncand + k] = sfill[k]; }
    }
    __syncthreads();
    int ntot = ncand + nfill;

    for (int s = 0; s < 32; s++) {
        float bs = -1e30f;
        int bi = 0x7fffffff;
        int bsl = -1;
        for (int c = t; c < ntot; c += 256) {
            float v = cs[c];
            int id = ci[c];
            if (v > bs || (v == bs && id < bi)) { bs = v; bi = id; bsl = c; }
        }
        rs[t] = bs; ri[t] = bi; rslot[t] = bsl;
        __syncthreads();
        for (int off = 128; off > 0; off >>= 1) {
            if (t < off) {
                if (rs[t + off] > rs[t] || (rs[t + off] == rs[t] && ri[t + off] < ri[t])) {
                    rs[t] = rs[t + off]; ri[t] = ri[t + off]; rslot[t] = rslot[t + off];
                }
            }
            __syncthreads();
        }
        if (t == 0) { pidx[s] = ri[0]; cs[rslot[0]] = -1e30f; }
        __syncthreads();
    }

    if (t == 0) sfound = 0;
    __syncthreads();
    for (int base = 0; base < 90000; base += 2048) {
        if (sfound >= 32) break;
        int f[8];
        int c8 = 0;
#pragma unroll
        for (int u = 0; u < 8; u++) {
            int i = base + t * 8 + u;
            int fl = (i < 90000 && negf[i] != 0) ? 1 : 0;
            f[u] = fl;
            c8 += fl;
        }
        spart[t] = c8;
        __syncthreads();
        for (int off = 1; off < 256; off <<= 1) {
            int v = (t >= off) ? spart[t - off] : 0;
            __syncthreads();
            spart[t] += v;
            __syncthreads();
        }
        int pref = sfound + spart[t] - c8;
        int total = spart[255];
#pragma unroll
        for (int u = 0; u < 8; u++) {
            if (f[u]) { if (pref < 32) nidx[pref] = base + t * 8 + u; pref++; }
        }
        __syncthreads();
        if (t == 0) sfound += total;
        __syncthreads();
    }
    __syncthreads();
    if (t == 0) {
        int nf = min(sfound, 32);
        for (int s = nf; s < 32; s++) nidx[s] = s;
    }
}

// ---------------- finalize: proposals, losses, index outputs ----------------
__global__ __launch_bounds__(64) void finalize_kernel(const float* __restrict__ cpart,
                                                      const float* __restrict__ rpart,
                                                      const float* __restrict__ bcls,
                                                      const float* __restrict__ breg,
                                                      const int* __restrict__ pidx,
                                                      const int* __restrict__ nidx,
                                                      const int* __restrict__ aarg,
                                                      const float* __restrict__ gt,
                                                      const int* __restrict__ gtc,
                                                      float* __restrict__ out) {
#pragma clang fp contract(off)
    const int PROP_OFF = 1 + 2560000;
    int t = threadIdx.x;  // 64 threads = 1 wave
    int n = (t < 32) ? pidx[t] : nidx[t - 32];
    int a = n % 9;
    int q = n / 9;
    int iy = q % 100;
    int ix = q / 100;
    int p = iy * 100 + ix;

    float l0 = bcls[a * 2 + 0], l1 = bcls[a * 2 + 1];
    for (int c = 0; c < 4; c++) {
        l0 += cpart[(c * 18 + a * 2 + 0) * 10000 + p];
        l1 += cpart[(c * 18 + a * 2 + 1) * 10000 + p];
    }
    float m = fmaxf(l0, l1);
    float lse = m + logf(expf(l0 - m) + expf(l1 - m));
    float logp = ((t < 32) ? l1 : l0) - lse;
    float cls_sum = logp;
#pragma unroll
    for (int off = 32; off > 0; off >>= 1) cls_sum += __shfl_down(cls_sum, off);

    float reg_sum = 0.f;
    if (t < 32) {
        float offv[4];
#pragma unroll
        for (int k = 0; k < 4; k++) {
            float v = breg[a * 4 + k];
            for (int c = 0; c < 4; c++) v += rpart[(c * 36 + a * 4 + k) * 10000 + p];
            offv[k] = v;
        }
        float x0, y0, x1, y1, aa;
        anchor_box(n, x0, y0, x1, y1, aa);
        float w = x1 - x0, h = y1 - y0;
        float cx = x0 + 0.5f * w, cy = y0 + 0.5f * h;
        float ncx = cx + offv[0] * w, ncy = cy + offv[1] * h;
        float nw = w * expf(offv[2]), nh = h * expf(offv[3]);
        out[PROP_OFF + t * 4 + 0] = ncx - nw * 0.5f;
        out[PROP_OFF + t * 4 + 1] = ncy - nh * 0.5f;
        out[PROP_OFF + t * 4 + 2] = ncx + nw * 0.5f;
        out[PROP_OFF + t * 4 + 3] = ncy + nh * 0.5f;

        int j = aarg[n];
        float g0 = gt[j * 4 + 0], g1 = gt[j * 4 + 1];
        float g2 = gt[j * 4 + 2], g3 = gt[j * 4 + 3];
        float gw = g2 - g0, gh = g3 - g1;
        float gcx = g0 + 0.5f * gw, gcy = g1 + 0.5f * gh;
        float tg[4];
        tg[0] = (gcx - cx) / w;
        tg[1] = (gcy - cy) / h;
        tg[2] = logf(gw / w);
        tg[3] = logf(gh / h);
#pragma unroll
        for (int k = 0; k < 4; k++) {
            float d = tg[k] - offv[k];
            float ad = fabsf(d);
            reg_sum += (ad < 1.f) ? 0.5f * d * d : ad - 0.5f;
        }
        out[PROP_OFF + 128 + t] = (float)n;
        out[PROP_OFF + 160 + t] = (float)gtc[j];
    }
#pragma unroll
    for (int off = 32; off > 0; off >>= 1) reg_sum += __shfl_down(reg_sum, off);
    if (t == 0) {
        float cls_loss = -(cls_sum / 64.f);
        float reg_loss = reg_sum / 128.f;
        out[0] = cls_loss + 5.f * reg_loss;
    }
}

// ---------------- launch ----------------
extern "C" void kernel_launch(void* const* d_in, const int* in_sizes, int n_in,
                              void* d_out, int out_size, void* d_ws, size_t ws_size,
                              hipStream_t stream) {
    const float* img = (const float*)d_in[0];
    const float* gt  = (const float*)d_in[1];
    const int*   gtc = (const int*)d_in[2];
    const float* w1  = (const float*)d_in[3];
    const float* b1  = (const float*)d_in[4];
    const float* w2  = (const float*)d_in[5];
    const float* b2  = (const float*)d_in[6];
    const float* wr  = (const float*)d_in[7];
    const float* br  = (const float*)d_in[8];
    const float* wc  = (const float*)d_in[9];
    const float* bc  = (const float*)d_in[10];
    const float* wg  = (const float*)d_in[11];
    const float* bg  = (const float*)d_in[12];
    float* out = (float*)d_out;
    float* ws = (float*)d_ws;

    unsigned short* f1t  = (unsigned short*)(ws + OFF_F1T);
    unsigned short* fmt  = (unsigned short*)(ws + OFF_FMT);
    unsigned short* w9_2 = (unsigned short*)(ws + OFF_W9_2);
    unsigned short* w9_3 = (unsigned short*)(ws + OFF_W9_3);
    float* hbuf  = ws + OFF_HBUF;
    float* cpart = ws + OFF_CPART;
    float* rpart = ws + OFF_RPART;
    float* wt1   = ws + OFF_WT1;
    float* wtc   = ws + OFF_WTC;
    float* wtg   = ws + OFF_WTG;
    int*   aarg  = (int*)(ws + OFF_AARG);
    float* psc   = ws + OFF_PSC;
    int*   negf  = (int*)(ws + OFF_NEGF);
    unsigned int* gtmax = (unsigned int*)(ws + OFF_GTMAX);
    unsigned int* cnt   = gtmax + 64;
    int*   pidx  = (int*)(ws + OFF_PIDX);
    int*   nidx  = (int*)(ws + OFF_NIDX);
    float* cands = ws + OFF_CANDS;
    int*   candi = (int*)(ws + OFF_CANDI);
    float* fm    = out + 1;   // fm lives directly in the output buffer (f32)

    init_kernel<<<dim3(1), dim3(128), 0, stream>>>(gtmax);
    zero_kernel<<<dim3((ZERO_F / 4 + 255) / 256), dim3(256), 0, stream>>>((float4*)ws, ZERO_F / 4);
    transpose_w<<<dim3(37), dim3(256), 0, stream>>>(w1, wt1, 64, 147);
    transpose_w<<<dim3(18), dim3(256), 0, stream>>>(wc, wtc, 18, 256);
    transpose_w<<<dim3(36), dim3(256), 0, stream>>>(wg, wtg, 36, 256);
    repack_w<<<dim3(576), dim3(256), 0, stream>>>(w2, w9_2, 64);
    repack_w<<<dim3(2304), dim3(256), 0, stream>>>(wr, w9_3, 256);

    conv1_kernel<<<dim3(25, 25), dim3(256), 0, stream>>>(img, wt1, b1, f1t);
    conv_gemm<64, 402, 4, true><<<dim3(157, 2), dim3(256), 0, stream>>>(f1t, w9_2, b2, fm, fmt);
    conv_gemm<256, 102, 1, false><<<dim3(157, 2), dim3(256), 0, stream>>>(fmt, w9_3, br, hbuf, nullptr);
    head_kernel<<<dim3(40, 4), dim3(256), 0, stream>>>(hbuf, wtc, wtg, cpart, rpart);

    iou_pass1<<<dim3(352), dim3(256), 0, stream>>>(gt, aarg, gtmax);
    iou_pass2<<<dim3(352), dim3(256), 0, stream>>>(gt, gtmax, psc, negf, cands, candi, cnt);
    select_kernel<<<dim3(1), dim3(256), 0, stream>>>(psc, negf, cands, candi, cnt, pidx, nidx);
    finalize_kernel<<<dim3(1), dim3(64), 0, stream>>>(cpart, rpart, bc, bg, pidx, nidx,
                                                      aarg, gt, gtc, out);
}

// Round 4
// 411.247 us; speedup vs baseline: 3.1017x; 1.2422x over previous
//
#include <hip/hip_runtime.h>
#include <math.h>

// RegionProposalNetwork on MI355X (gfx950).
// Round 4: conv1 moved to fused-im2col bf16 MFMA (K=147 padded to 160);
// border-only zeroing of padded transposed feature maps.
// Selection path (anchors/IoU/top-k) unchanged, exact f32.

#define CAP 4096

typedef __attribute__((ext_vector_type(8))) short bf16x8;
typedef __attribute__((ext_vector_type(4))) float f32x4;

// ---------------- workspace layout (float offsets) ----------------
#define OFF_F1T     0          // 5,171,328 f = 402*402*64 bf16 (conv1 out, padded transposed)
#define OFF_HBUF    0          // 2,560,000 f (rpn hidden; overlays F1T which is dead by then)
#define OFF_FMT     5171328    // 1,331,712 f = 102*102*256 bf16 (fm, padded transposed)
#define OFF_CPART   6503040    //   720,000 (4*18*10000)
#define OFF_RPART   7223040    // 1,440,000 (4*36*10000)
#define OFF_WA1     8663040    //     5,120 f = 64*160 bf16 (conv1 weights, K-padded)
#define OFF_W9_2    8672448    //    73,728 f = 9*256*64 bf16
#define OFF_W9_3    8746176    //   294,912 f = 9*256*256 bf16
#define OFF_WTC     9041088    //     4,608 [256][18] f32
#define OFF_WTG     9045696    //     9,216 [256][36] f32
#define OFF_AARG    9054912    //    90,000 (int)
#define OFF_PSC     9144912    //    90,000
#define OFF_NEGF    9234912    //    90,000 (int)
#define OFF_GTMAX   9324912    //    64 uint + counter (pad 80)
#define OFF_PIDX    9324992    //    32 (int)
#define OFF_NIDX    9325024    //    32 (int)
#define OFF_CANDS   9325056    //    4,096
#define OFF_CANDI   9329152    //    4,096 (int)

__device__ __forceinline__ unsigned short f2bf(float f) {   // RNE f32->bf16
    unsigned int u = __float_as_uint(f);
    u += 0x7fffu + ((u >> 16) & 1u);
    return (unsigned short)(u >> 16);
}

// ---------------- selection-path exact math ----------------
__device__ __forceinline__ void anchor_box(int i, float& x0, float& y0,
                                           float& x1, float& y1, float& area) {
#pragma clang fp contract(off)
    const float sizes[3]  = {128.f, 256.f, 512.f};
    const float ratios[3] = {0.5f, 1.f, 2.f};
    int a = i % 9;
    int q = i / 9;
    int iy = q % 100;
    int ix = q / 100;
    int s = a / 3, r = a % 3;
    float sq = sqrtf(ratios[r]);
    float w = sizes[s] * sq;
    float h = sizes[s] / sq;
    float cx = ((float)ix + 0.5f) * 16.0f;
    float cy = ((float)iy + 0.5f) * 16.0f;
    x0 = cx - w * 0.5f;
    y0 = cy - h * 0.5f;
    x1 = x0 + w;
    y1 = y0 + h;
    area = (x1 - x0) * (y1 - y0);
}

__device__ __forceinline__ float iou_one(float ax0, float ay0, float ax1, float ay1, float aa,
                                         float bx0, float by0, float bx1, float by1, float ab) {
#pragma clang fp contract(off)
    float ltx = fmaxf(ax0, bx0), lty = fmaxf(ay0, by0);
    float rbx = fminf(ax1, bx1), rby = fminf(ay1, by1);
    float iw = fmaxf(rbx - ltx, 0.0f);
    float ih = fmaxf(rby - lty, 0.0f);
    float inter = iw * ih;
    return inter / ((aa + ab) - inter);
}

// ---------------- small utility kernels ----------------
__global__ void init_kernel(unsigned int* p) {
    int t = threadIdx.x;
    if (t < 65) p[t] = 0u;   // gtmax[64] + cand counter
}

// zero only the padding borders of f1t (402x402x64) and fmt (102x102x256)
__global__ void pad_zero(unsigned int* __restrict__ f1t_u, unsigned int* __restrict__ fmt_u) {
    int i = blockIdx.x * 256 + threadIdx.x;
    if (i < 1604 * 32) {
        int p = i >> 5, part = i & 31;
        int x, y;
        if (p < 804) { y = (p < 402) ? 0 : 401; x = p % 402; }
        else { int j = p - 804; x = (j < 400) ? 0 : 401; y = 1 + (j % 400); }
        f1t_u[(y * 402 + x) * 32 + part] = 0u;
    } else {
        int i2 = i - 1604 * 32;
        if (i2 < 404 * 128) {
            int p = i2 >> 7, part = i2 & 127;
            int x, y;
            if (p < 204) { y = (p < 102) ? 0 : 101; x = p % 102; }
            else { int j = p - 204; x = (j < 100) ? 0 : 101; y = 1 + (j % 100); }
            fmt_u[(y * 102 + x) * 128 + part] = 0u;
        }
    }
}

__global__ void transpose_w(const float* __restrict__ src,
                            float* __restrict__ dst, int C, int K) {
    int idx = blockIdx.x * 256 + threadIdx.x;
    if (idx < C * K) {
        int c = idx / K;
        int k = idx - c * K;
        dst[k * C + c] = src[idx];
    }
}

// conv1 weights [64][3][7][7] f32 -> [64][160] bf16 (k = ic*49+ky*7+kx, pad 147..159 = 0)
__global__ void repack_w1(const float* __restrict__ src, unsigned short* __restrict__ dst) {
    int i = blockIdx.x * 256 + threadIdx.x;
    if (i >= 64 * 160) return;
    int oc = i / 160, k = i - oc * 160;
    dst[i] = (k < 147) ? f2bf(src[oc * 147 + k]) : (unsigned short)0;
}

// repack [oc][ic][3][3] f32 -> [kk][oc][ic] bf16
__global__ void repack_w(const float* __restrict__ src, unsigned short* __restrict__ dst,
                         int IC) {
    int d = blockIdx.x * 256 + threadIdx.x;
    int tot = 9 * 256 * IC;
    if (d >= tot) return;
    int kk = d / (256 * IC);
    int rem = d - kk * 256 * IC;
    int oc = rem / IC;
    int ic = rem - oc * IC;
    dst[d] = f2bf(src[(oc * IC + ic) * 9 + kk]);
}

// ---------------- conv1 via MFMA: 3->64, 7x7, s4, p3, fused im2col ----------------
// Block: 4 waves, tile = 64 oc x 64 px (one output row oy, ox = xb*64..+63).
// K = 147 padded to 160. Writes f1t[(oy+1)*402 + ox+1][64] bf16.
__global__ __launch_bounds__(256) void conv1_mfma(const float* __restrict__ img,
                                                  const unsigned short* __restrict__ wA, // [64][160]
                                                  const float* __restrict__ bias,
                                                  unsigned short* __restrict__ f1t) {
    __shared__ float sin_[3 * 7 * 260];        // input window [ic][ky][c], c=4*px+kx
    __shared__ unsigned short tileT[64 * 72];  // C transpose staging [px][oc], padded row 72
    int t = threadIdx.x;
    int wave = t >> 6, lane = t & 63;
    int quad = lane >> 4, l16 = lane & 15;
    int oy = blockIdx.y;
    int ox0 = blockIdx.x * 64;
    int gx0 = ox0 * 4 - 3;
    int gy0 = 4 * oy - 3;
    for (int idx = t; idx < 3 * 7 * 259; idx += 256) {
        int ic = idx / (7 * 259);
        int r = idx - ic * 7 * 259;
        int ky = r / 259, c = r - ky * 259;
        int gy = gy0 + ky, gx = gx0 + c;
        float v = 0.f;
        if (gy >= 0 && gy < 1600 && gx >= 0 && gx < 1600)
            v = img[(ic * 1600 + gy) * 1600 + gx];
        sin_[(ic * 7 + ky) * 260 + c] = v;
    }
    bf16x8 afr[5];
    {
        const bf16x8* ap = (const bf16x8*)(wA + (wave * 16 + l16) * 160 + quad * 8);
#pragma unroll
        for (int c = 0; c < 5; c++) afr[c] = ap[c * 4];
    }
    __syncthreads();

    f32x4 acc[4];
#pragma unroll
    for (int j = 0; j < 4; j++) acc[j] = (f32x4){0.f, 0.f, 0.f, 0.f};
    int q8 = quad * 8;
    int col4[4];
#pragma unroll
    for (int j = 0; j < 4; j++) col4[j] = 4 * (j * 16 + l16);

#pragma unroll
    for (int ch = 0; ch < 5; ch++) {
        float val[4][8];
#pragma unroll
        for (int jj = 0; jj < 8; jj++) {
            int k = ch * 32 + q8 + jj;
            int ic = (k * 335) >> 14;          // k/49 for k<160
            int r = k - ic * 49;
            int ky = (r * 37) >> 8;            // r/7 for r<49
            int kx = r - ky * 7;
            bool valid = (k < 147);
            int base = valid ? ((ic * 7 + ky) * 260 + kx) : 0;
#pragma unroll
            for (int j = 0; j < 4; j++) {
                float v = sin_[base + col4[j]];
                val[j][jj] = valid ? v : 0.f;
            }
        }
#pragma unroll
        for (int j = 0; j < 4; j++) {
            bf16x8 b;
#pragma unroll
            for (int jj = 0; jj < 8; jj++) b[jj] = (short)f2bf(val[j][jj]);
            acc[j] = __builtin_amdgcn_mfma_f32_16x16x32_bf16(afr[ch], b, acc[j], 0, 0, 0);
        }
    }
    // epilogue: C[m=oc16][n=px16]: m = quad*4+reg, n = l16 (per j tile)
#pragma unroll
    for (int reg = 0; reg < 4; reg++) {
        int oc = wave * 16 + quad * 4 + reg;
        float bv = bias[oc];
#pragma unroll
        for (int j = 0; j < 4; j++) {
            int px = j * 16 + l16;
            tileT[px * 72 + oc] = f2bf(fmaxf(acc[j][reg] + bv, 0.f));
        }
    }
    __syncthreads();
    int px = t >> 2, part = t & 3;
    int ox = ox0 + px;
    if (ox < 400) {
        int row = (oy + 1) * 402 + ox + 1;
        uint4 v = *(const uint4*)(tileT + px * 72 + part * 16);
        *(uint4*)(f1t + row * 64 + part * 16) = v;
    }
}

// ---------------- implicit-GEMM conv via MFMA bf16 ----------------
// C[256 oc][10000 px] = sum over 9 passes, K=ICC per pass.
// Bt: padded transposed input [row][ICC] bf16, row = (S*y+ky)*RS + S*x+kx.
// A9: [pass][oc][ICC] bf16. Wave tile: 32 oc x 64 px. Block = 4 waves = 128 oc x 64 px.
template<int ICC, int RS, int S, bool WRT>
__global__ __launch_bounds__(256) void conv_gemm(const unsigned short* __restrict__ Bt,
                                                 const unsigned short* __restrict__ A9,
                                                 const float* __restrict__ bias,
                                                 float* __restrict__ outF,
                                                 unsigned short* __restrict__ outT) {
    int t = threadIdx.x;
    int wave = t >> 6, lane = t & 63;
    int quad = lane >> 4, l16 = lane & 15;
    int n0 = blockIdx.x * 64;
    int oc0 = blockIdx.y * 128 + wave * 32;
    int y[4], x[4];
#pragma unroll
    for (int j = 0; j < 4; j++) {
        int p = n0 + j * 16 + l16;
        int pe = min(p, 9999);              // clamp: OOB lanes compute discarded garbage
        y[j] = pe / 100;
        x[j] = pe - y[j] * 100;
    }
    f32x4 acc[2][4];
#pragma unroll
    for (int a = 0; a < 2; a++)
#pragma unroll
        for (int j = 0; j < 4; j++) acc[a][j] = (f32x4){0.f, 0.f, 0.f, 0.f};

    const int KCH = ICC / 32;
    for (int pass = 0; pass < 9; pass++) {
        int ky = pass / 3, kx = pass - (pass / 3) * 3;
        const bf16x8* aP0 = (const bf16x8*)(A9 + (size_t)pass * 256 * ICC + (oc0 + l16) * ICC + quad * 8);
        const bf16x8* aP1 = (const bf16x8*)(A9 + (size_t)pass * 256 * ICC + (oc0 + 16 + l16) * ICC + quad * 8);
        const bf16x8* bP[4];
#pragma unroll
        for (int j = 0; j < 4; j++) {
            int r = (S * y[j] + ky) * RS + S * x[j] + kx;
            bP[j] = (const bf16x8*)(Bt + (size_t)r * ICC + quad * 8);
        }
#pragma unroll
        for (int kc = 0; kc < KCH; kc++) {
            bf16x8 a0 = aP0[kc * 4];
            bf16x8 a1 = aP1[kc * 4];
#pragma unroll
            for (int j = 0; j < 4; j++) {
                bf16x8 b = bP[j][kc * 4];
                acc[0][j] = __builtin_amdgcn_mfma_f32_16x16x32_bf16(a0, b, acc[0][j], 0, 0, 0);
                acc[1][j] = __builtin_amdgcn_mfma_f32_16x16x32_bf16(a1, b, acc[1][j], 0, 0, 0);
            }
        }
    }
#pragma unroll
    for (int a = 0; a < 2; a++) {
#pragma unroll
        for (int reg = 0; reg < 4; reg++) {
            int oc = oc0 + a * 16 + quad * 4 + reg;
            float bv = bias[oc];
#pragma unroll
            for (int j = 0; j < 4; j++) {
                int p = n0 + j * 16 + l16;
                if (p < 10000) {
                    float v = fmaxf(acc[a][j][reg] + bv, 0.f);
                    outF[oc * 10000 + p] = v;
                    if (WRT) {
                        int yy = p / 100, xx = p - (p / 100) * 100;
                        int r = (yy + 1) * 102 + xx + 1;
                        outT[r * 256 + oc] = f2bf(v);
                    }
                }
            }
        }
    }
}

// ---------------- 1x1 heads: partial sums over 64-channel chunks ----------------
__global__ __launch_bounds__(256) void head_kernel(const float* __restrict__ hbuf,
                                                   const float* __restrict__ wtc,  // [256][18]
                                                   const float* __restrict__ wtg,  // [256][36]
                                                   float* __restrict__ cpart,      // [4][18][10000]
                                                   float* __restrict__ rpart) {    // [4][36][10000]
    int p = blockIdx.x * 256 + threadIdx.x;
    int ch = blockIdx.y;
    int ic0 = ch * 64;
    if (p >= 10000) return;
    float acc[54];
#pragma unroll
    for (int j = 0; j < 54; j++) acc[j] = 0.f;
    for (int ic = 0; ic < 64; ic++) {
        float v = hbuf[(ic0 + ic) * 10000 + p];
        const float* wc_ = wtc + (ic0 + ic) * 18;
#pragma unroll
        for (int j = 0; j < 18; j++) acc[j] += v * wc_[j];
        const float* wg_ = wtg + (ic0 + ic) * 36;
#pragma unroll
        for (int j = 0; j < 36; j++) acc[18 + j] += v * wg_[j];
    }
    for (int j = 0; j < 18; j++) cpart[(ch * 18 + j) * 10000 + p] = acc[j];
    for (int j = 0; j < 36; j++) rpart[(ch * 36 + j) * 10000 + p] = acc[18 + j];
}

// ---------------- IoU pass 1: anc argmax + per-gt max ----------------
__global__ __launch_bounds__(256) void iou_pass1(const float* __restrict__ gt,
                                                 int* __restrict__ aarg,
                                                 unsigned int* __restrict__ gtmax) {
    __shared__ float sg[64][4];
    __shared__ float sarea[64];
    __shared__ unsigned int smax[64];
    int t = threadIdx.x;
    if (t < 64) {
#pragma clang fp contract(off)
        float b0 = gt[t * 4 + 0], b1 = gt[t * 4 + 1];
        float b2 = gt[t * 4 + 2], b3 = gt[t * 4 + 3];
        sg[t][0] = b0; sg[t][1] = b1; sg[t][2] = b2; sg[t][3] = b3;
        sarea[t] = (b2 - b0) * (b3 - b1);
        smax[t] = 0u;
    }
    __syncthreads();
    int i = blockIdx.x * 256 + t;
    int iq = min(i, 89999);              // keep all 64 lanes active for the shuffles
    float x0, y0, x1, y1, aa;
    anchor_box(iq, x0, y0, x1, y1, aa);
    float best = -1.f;
    int bestj = 0;
    for (int j = 0; j < 64; j++) {
        float v = iou_one(x0, y0, x1, y1, aa, sg[j][0], sg[j][1], sg[j][2], sg[j][3], sarea[j]);
        if (v > best) { best = v; bestj = j; }
        float vm = v;
#pragma unroll
        for (int off = 32; off > 0; off >>= 1) vm = fmaxf(vm, __shfl_xor(vm, off));
        if ((t & 63) == 0) atomicMax(&smax[j], __float_as_uint(vm));
    }
    if (i < 90000) aarg[i] = bestj;
    __syncthreads();
    if (t < 64) atomicMax(&gtmax[t], smax[t]);
}

// ---------------- IoU pass 2: labels + pos compaction ----------------
__global__ __launch_bounds__(256) void iou_pass2(const float* __restrict__ gt,
                                                 const unsigned int* __restrict__ gtmax,
                                                 float* __restrict__ psc,
                                                 int* __restrict__ negf,
                                                 float* __restrict__ cand_s,
                                                 int* __restrict__ cand_i,
                                                 unsigned int* __restrict__ cnt) {
    __shared__ float sg[64][4];
    __shared__ float sarea[64];
    __shared__ float sgm[64];
    int t = threadIdx.x;
    if (t < 64) {
#pragma clang fp contract(off)
        float b0 = gt[t * 4 + 0], b1 = gt[t * 4 + 1];
        float b2 = gt[t * 4 + 2], b3 = gt[t * 4 + 3];
        sg[t][0] = b0; sg[t][1] = b1; sg[t][2] = b2; sg[t][3] = b3;
        sarea[t] = (b2 - b0) * (b3 - b1);
        sgm[t] = __uint_as_float(gtmax[t]);
    }
    __syncthreads();
    int i = blockIdx.x * 256 + t;
    if (i >= 90000) return;
    float x0, y0, x1, y1, aa;
    anchor_box(i, x0, y0, x1, y1, aa);
    float best = -1.f;
    bool isbest = false;
    for (int j = 0; j < 64; j++) {
        float v = iou_one(x0, y0, x1, y1, aa, sg[j][0], sg[j][1], sg[j][2], sg[j][3], sarea[j]);
        if (v > best) best = v;
        if (v == sgm[j]) isbest = true;
    }
    float label = -1.f;
    if (best < 0.2f) label = 0.f;
    if (isbest) label = 1.f;
    if (best > 0.7f) label = 1.f;
    psc[i] = (label == 1.f) ? best : -1.0f;
    negf[i] = (label == 0.f) ? 1 : 0;
    if (label == 1.f) {
        unsigned int p = atomicAdd(cnt, 1u);
        if (p < CAP) { cand_s[p] = best; cand_i[p] = i; }
    }
}

// ---------------- top-k selection (jax.lax.top_k semantics) ----------------
__global__ __launch_bounds__(256) void select_kernel(const float* __restrict__ psc,
                                                     const int* __restrict__ negf,
                                                     const float* __restrict__ cand_s,
                                                     const int* __restrict__ cand_i,
                                                     const unsigned int* __restrict__ cnt,
                                                     int* __restrict__ pidx,
                                                     int* __restrict__ nidx) {
    __shared__ float cs[CAP + 32];
    __shared__ int ci[CAP + 32];
    __shared__ int spart[256];
    __shared__ int sfound;
    __shared__ int sfill[32];
    __shared__ float rs[256];
    __shared__ int ri[256];
    __shared__ int rslot[256];
    int t = threadIdx.x;
    int ncand = min((int)*cnt, CAP);
    for (int c = t; c < ncand; c += 256) { cs[c] = cand_s[c]; ci[c] = cand_i[c]; }
    if (t == 0) sfound = 0;
    __syncthreads();

    int nfill = 0;
    if (ncand < 32) {
        for (int base = 0; base < 90000; base += 2048) {
            if (sfound >= 32) break;
            int f[8];
            int c8 = 0;
#pragma unroll
            for (int u = 0; u < 8; u++) {
                int i = base + t * 8 + u;
                int fl = (i < 90000 && psc[i] < 0.f) ? 1 : 0;
                f[u] = fl;
                c8 += fl;
            }
            spart[t] = c8;
            __syncthreads();
            for (int off = 1; off < 256; off <<= 1) {
                int v = (t >= off) ? spart[t - off] : 0;
                __syncthreads();
                spart[t] += v;
                __syncthreads();
            }
            int pref = sfound + spart[t] - c8;
            int total = spart[255];
#pragma unroll
            for (int u = 0; u < 8; u++) {
                if (f[u]) { if (pref < 32) sfill[pref] = base + t * 8 + u; pref++; }
            }
            __syncthreads();
            if (t == 0) sfound += total;
            __syncthreads();
        }
        nfill = min(sfound, 32);
        for (int k = t; k < nfill; k += 256) { cs[ncand + k] = -1.0f; ci[ncand + k] = sfill[k]; }
    }
    __syncthreads();
    int ntot = ncand + nfill;

    for (int s = 0; s < 32; s++) {
        float bs = -1e30f;
        int bi = 0x7fffffff;
        int bsl = -1;
        for (int c = t; c < ntot; c += 256) {
            float v = cs[c];
            int id = ci[c];
            if (v > bs || (v == bs && id < bi)) { bs = v; bi = id; bsl = c; }
        }
        rs[t] = bs; ri[t] = bi; rslot[t] = bsl;
        __syncthreads();
        for (int off = 128; off > 0; off >>= 1) {
            if (t < off) {
                if (rs[t + off] > rs[t] || (rs[t + off] == rs[t] && ri[t + off] < ri[t])) {
                    rs[t] = rs[t + off]; ri[t] = ri[t + off]; rslot[t] = rslot[t + off];
                }
            }
            __syncthreads();
        }
        if (t == 0) { pidx[s] = ri[0]; cs[rslot[0]] = -1e30f; }
        __syncthreads();
    }

    if (t == 0) sfound = 0;
    __syncthreads();
    for (int base = 0; base < 90000; base += 2048) {
        if (sfound >= 32) break;
        int f[8];
        int c8 = 0;
#pragma unroll
        for (int u = 0; u < 8; u++) {
            int i = base + t * 8 + u;
            int fl = (i < 90000 && negf[i] != 0) ? 1 : 0;
            f[u] = fl;
            c8 += fl;
        }
        spart[t] = c8;
        __syncthreads();
        for (int off = 1; off < 256; off <<= 1) {
            int v = (t >= off) ? spart[t - off] : 0;
            __syncthreads();
            spart[t] += v;
            __syncthreads();
        }
        int pref = sfound + spart[t] - c8;
        int total = spart[255];
#pragma unroll
        for (int u = 0; u < 8; u++) {
            if (f[u]) { if (pref < 32) nidx[pref] = base + t * 8 + u; pref++; }
        }
        __syncthreads();
        if (t == 0) sfound += total;
        __syncthreads();
    }
    __syncthreads();
    if (t == 0) {
        int nf = min(sfound, 32);
        for (int s = nf; s < 32; s++) nidx[s] = s;
    }
}

// ---------------- finalize: proposals, losses, index outputs ----------------
__global__ __launch_bounds__(64) void finalize_kernel(const float* __restrict__ cpart,
                                                      const float* __restrict__ rpart,
                                                      const float* __restrict__ bcls,
                                                      const float* __restrict__ breg,
                                                      const int* __restrict__ pidx,
                                                      const int* __restrict__ nidx,
                                                      const int* __restrict__ aarg,
                                                      const float* __restrict__ gt,
                                                      const int* __restrict__ gtc,
                                                      float* __restrict__ out) {
#pragma clang fp contract(off)
    const int PROP_OFF = 1 + 2560000;
    int t = threadIdx.x;  // 64 threads = 1 wave
    int n = (t < 32) ? pidx[t] : nidx[t - 32];
    int a = n % 9;
    int q = n / 9;
    int iy = q % 100;
    int ix = q / 100;
    int p = iy * 100 + ix;

    float l0 = bcls[a * 2 + 0], l1 = bcls[a * 2 + 1];
    for (int c = 0; c < 4; c++) {
        l0 += cpart[(c * 18 + a * 2 + 0) * 10000 + p];
        l1 += cpart[(c * 18 + a * 2 + 1) * 10000 + p];
    }
    float m = fmaxf(l0, l1);
    float lse = m + logf(expf(l0 - m) + expf(l1 - m));
    float logp = ((t < 32) ? l1 : l0) - lse;
    float cls_sum = logp;
#pragma unroll
    for (int off = 32; off > 0; off >>= 1) cls_sum += __shfl_down(cls_sum, off);

    float reg_sum = 0.f;
    if (t < 32) {
        float offv[4];
#pragma unroll
        for (int k = 0; k < 4; k++) {
            float v = breg[a * 4 + k];
            for (int c = 0; c < 4; c++) v += rpart[(c * 36 + a * 4 + k) * 10000 + p];
            offv[k] = v;
        }
        float x0, y0, x1, y1, aa;
        anchor_box(n, x0, y0, x1, y1, aa);
        float w = x1 - x0, h = y1 - y0;
        float cx = x0 + 0.5f * w, cy = y0 + 0.5f * h;
        float ncx = cx + offv[0] * w, ncy = cy + offv[1] * h;
        float nw = w * expf(offv[2]), nh = h * expf(offv[3]);
        out[PROP_OFF + t * 4 + 0] = ncx - nw * 0.5f;
        out[PROP_OFF + t * 4 + 1] = ncy - nh * 0.5f;
        out[PROP_OFF + t * 4 + 2] = ncx + nw * 0.5f;
        out[PROP_OFF + t * 4 + 3] = ncy + nh * 0.5f;

        int j = aarg[n];
        float g0 = gt[j * 4 + 0], g1 = gt[j * 4 + 1];
        float g2 = gt[j * 4 + 2], g3 = gt[j * 4 + 3];
        float gw = g2 - g0, gh = g3 - g1;
        float gcx = g0 + 0.5f * gw, gcy = g1 + 0.5f * gh;
        float tg[4];
        tg[0] = (gcx - cx) / w;
        tg[1] = (gcy - cy) / h;
        tg[2] = logf(gw / w);
        tg[3] = logf(gh / h);
#pragma unroll
        for (int k = 0; k < 4; k++) {
            float d = tg[k] - offv[k];
            float ad = fabsf(d);
            reg_sum += (ad < 1.f) ? 0.5f * d * d : ad - 0.5f;
        }
        out[PROP_OFF + 128 + t] = (float)n;
        out[PROP_OFF + 160 + t] = (float)gtc[j];
    }
#pragma unroll
    for (int off = 32; off > 0; off >>= 1) reg_sum += __shfl_down(reg_sum, off);
    if (t == 0) {
        float cls_loss = -(cls_sum / 64.f);
        float reg_loss = reg_sum / 128.f;
        out[0] = cls_loss + 5.f * reg_loss;
    }
}

// ---------------- launch ----------------
extern "C" void kernel_launch(void* const* d_in, const int* in_sizes, int n_in,
                              void* d_out, int out_size, void* d_ws, size_t ws_size,
                              hipStream_t stream) {
    const float* img = (const float*)d_in[0];
    const float* gt  = (const float*)d_in[1];
    const int*   gtc = (const int*)d_in[2];
    const float* w1  = (const float*)d_in[3];
    const float* b1  = (const float*)d_in[4];
    const float* w2  = (const float*)d_in[5];
    const float* b2  = (const float*)d_in[6];
    const float* wr  = (const float*)d_in[7];
    const float* br  = (const float*)d_in[8];
    const float* wc  = (const float*)d_in[9];
    const float* bc  = (const float*)d_in[10];
    const float* wg  = (const float*)d_in[11];
    const float* bg  = (const float*)d_in[12];
    float* out = (float*)d_out;
    float* ws = (float*)d_ws;

    unsigned short* f1t  = (unsigned short*)(ws + OFF_F1T);
    unsigned short* fmt  = (unsigned short*)(ws + OFF_FMT);
    unsigned short* wa1  = (unsigned short*)(ws + OFF_WA1);
    unsigned short* w9_2 = (unsigned short*)(ws + OFF_W9_2);
    unsigned short* w9_3 = (unsigned short*)(ws + OFF_W9_3);
    float* hbuf  = ws + OFF_HBUF;
    float* cpart = ws + OFF_CPART;
    float* rpart = ws + OFF_RPART;
    float* wtc   = ws + OFF_WTC;
    float* wtg   = ws + OFF_WTG;
    int*   aarg  = (int*)(ws + OFF_AARG);
    float* psc   = ws + OFF_PSC;
    int*   negf  = (int*)(ws + OFF_NEGF);
    unsigned int* gtmax = (unsigned int*)(ws + OFF_GTMAX);
    unsigned int* cnt   = gtmax + 64;
    int*   pidx  = (int*)(ws + OFF_PIDX);
    int*   nidx  = (int*)(ws + OFF_NIDX);
    float* cands = ws + OFF_CANDS;
    int*   candi = (int*)(ws + OFF_CANDI);
    float* fm    = out + 1;   // fm lives directly in the output buffer (f32)

    init_kernel<<<dim3(1), dim3(128), 0, stream>>>(gtmax);
    pad_zero<<<dim3(403), dim3(256), 0, stream>>>((unsigned int*)f1t, (unsigned int*)fmt);
    transpose_w<<<dim3(18), dim3(256), 0, stream>>>(wc, wtc, 18, 256);
    transpose_w<<<dim3(36), dim3(256), 0, stream>>>(wg, wtg, 36, 256);
    repack_w1<<<dim3(40), dim3(256), 0, stream>>>(w1, wa1);
    repack_w<<<dim3(576), dim3(256), 0, stream>>>(w2, w9_2, 64);
    repack_w<<<dim3(2304), dim3(256), 0, stream>>>(wr, w9_3, 256);

    conv1_mfma<<<dim3(7, 400), dim3(256), 0, stream>>>(img, wa1, b1, f1t);
    conv_gemm<64, 402, 4, true><<<dim3(157, 2), dim3(256), 0, stream>>>(f1t, w9_2, b2, fm, fmt);
    conv_gemm<256, 102, 1, false><<<dim3(157, 2), dim3(256), 0, stream>>>(fmt, w9_3, br, hbuf, nullptr);
    head_kernel<<<dim3(40, 4), dim3(256), 0, stream>>>(hbuf, wtc, wtg, cpart, rpart);

    iou_pass1<<<dim3(352), dim3(256), 0, stream>>>(gt, aarg, gtmax);
    iou_pass2<<<dim3(352), dim3(256), 0, stream>>>(gt, gtmax, psc, negf, cands, candi, cnt);
    select_kernel<<<dim3(1), dim3(256), 0, stream>>>(psc, negf, cands, candi, cnt, pidx, nidx);
    finalize_kernel<<<dim3(1), dim3(64), 0, stream>>>(cpart, rpart, bc, bg, pidx, nidx,
                                                      aarg, gt, gtc, out);
}

// Round 5
// 360.404 us; speedup vs baseline: 3.5393x; 1.1411x over previous
//
#include <hip/hip_runtime.h>
#include <math.h>

// RegionProposalNetwork on MI355X (gfx950).
// Round 5: conv_gemm re-gridded (1256 one-wave blocks) + register-pipelined
// loads (A pass-preload, B double-buffer prefetch) -- bit-identical arithmetic.
// head_kernel re-gridded. select_kernel rewritten on ballot bitmasks.
// Setup kernels merged. Selection path exact f32 as before.

#define CAP 4096

typedef __attribute__((ext_vector_type(8))) short bf16x8;
typedef __attribute__((ext_vector_type(4))) float f32x4;

// ---------------- workspace layout (float offsets) ----------------
#define OFF_F1T     0          // 5,171,328 f = 402*402*64 bf16 (conv1 out, padded transposed)
#define OFF_HBUF    0          // 2,560,000 f (rpn hidden; overlays F1T which is dead by then)
#define OFF_FMT     5171328    // 1,331,712 f = 102*102*256 bf16 (fm, padded transposed)
#define OFF_CPART   6503040    //   720,000 (4*18*10000)
#define OFF_RPART   7223040    // 1,440,000 (4*36*10000)
#define OFF_WA1     8663040    //     5,120 f = 64*160 bf16 (conv1 weights, K-padded)
#define OFF_W9_2    8672448    //    73,728 f = 9*256*64 bf16
#define OFF_W9_3    8746176    //   294,912 f = 9*256*256 bf16
#define OFF_WTC     9041088    //     4,608 [256][18] f32
#define OFF_WTG     9045696    //     9,216 [256][36] f32
#define OFF_AARG    9054912    //    90,000 (int)
#define OFF_NEGM    9144912    //     2,816 f = 1408 uint64 (neg label bitmask)
#define OFF_POSM    9147728    //     2,816 f = 1408 uint64 (pos label bitmask)
#define OFF_GTMAX   9150544    //    64 uint + counter (pad 80)
#define OFF_PIDX    9150624    //    32 (int)
#define OFF_NIDX    9150656    //    32 (int)
#define OFF_CANDS   9150688    //    4,096
#define OFF_CANDI   9154784    //    4,096 (int)

__device__ __forceinline__ unsigned short f2bf(float f) {   // RNE f32->bf16
    unsigned int u = __float_as_uint(f);
    u += 0x7fffu + ((u >> 16) & 1u);
    return (unsigned short)(u >> 16);
}

// ---------------- selection-path exact math ----------------
__device__ __forceinline__ void anchor_box(int i, float& x0, float& y0,
                                           float& x1, float& y1, float& area) {
#pragma clang fp contract(off)
    const float sizes[3]  = {128.f, 256.f, 512.f};
    const float ratios[3] = {0.5f, 1.f, 2.f};
    int a = i % 9;
    int q = i / 9;
    int iy = q % 100;
    int ix = q / 100;
    int s = a / 3, r = a % 3;
    float sq = sqrtf(ratios[r]);
    float w = sizes[s] * sq;
    float h = sizes[s] / sq;
    float cx = ((float)ix + 0.5f) * 16.0f;
    float cy = ((float)iy + 0.5f) * 16.0f;
    x0 = cx - w * 0.5f;
    y0 = cy - h * 0.5f;
    x1 = x0 + w;
    y1 = y0 + h;
    area = (x1 - x0) * (y1 - y0);
}

__device__ __forceinline__ float iou_one(float ax0, float ay0, float ax1, float ay1, float aa,
                                         float bx0, float by0, float bx1, float by1, float ab) {
#pragma clang fp contract(off)
    float ltx = fmaxf(ax0, bx0), lty = fmaxf(ay0, by0);
    float rbx = fminf(ax1, bx1), rby = fminf(ay1, by1);
    float iw = fmaxf(rbx - ltx, 0.0f);
    float ih = fmaxf(rby - lty, 0.0f);
    float inter = iw * ih;
    return inter / ((aa + ab) - inter);
}

// ---------------- merged setup: zero counters, pad borders, repack weights ----------------
__global__ __launch_bounds__(256) void setup_kernel(const float* __restrict__ wc, float* __restrict__ wtc,
                                                    const float* __restrict__ wg, float* __restrict__ wtg,
                                                    const float* __restrict__ w1, unsigned short* __restrict__ wa1,
                                                    const float* __restrict__ w2, unsigned short* __restrict__ w9_2,
                                                    const float* __restrict__ wr, unsigned short* __restrict__ w9_3,
                                                    unsigned int* __restrict__ f1t_u, unsigned int* __restrict__ fmt_u,
                                                    unsigned int* __restrict__ gtmax) {
    int i = blockIdx.x * 256 + threadIdx.x;
    if (i < 65) { gtmax[i] = 0u; return; }
    i -= 65;
    if (i < 103040) {   // zero pad borders of f1t / fmt
        if (i < 51328) {
            int p = i >> 5, part = i & 31;
            int x, y;
            if (p < 804) { y = (p < 402) ? 0 : 401; x = p % 402; }
            else { int j = p - 804; x = (j < 400) ? 0 : 401; y = 1 + (j % 400); }
            f1t_u[(y * 402 + x) * 32 + part] = 0u;
        } else {
            int i2 = i - 51328;
            int p = i2 >> 7, part = i2 & 127;
            int x, y;
            if (p < 204) { y = (p < 102) ? 0 : 101; x = p % 102; }
            else { int j = p - 204; x = (j < 100) ? 0 : 101; y = 1 + (j % 100); }
            fmt_u[(y * 102 + x) * 128 + part] = 0u;
        }
        return;
    }
    i -= 103040;
    if (i < 4608) { int c = i / 256, k = i - c * 256; wtc[k * 18 + c] = wc[i]; return; }
    i -= 4608;
    if (i < 9216) { int c = i / 256, k = i - c * 256; wtg[k * 36 + c] = wg[i]; return; }
    i -= 9216;
    if (i < 10240) {
        int oc = i / 160, k = i - oc * 160;
        wa1[i] = (k < 147) ? f2bf(w1[oc * 147 + k]) : (unsigned short)0;
        return;
    }
    i -= 10240;
    if (i < 147456) {
        int kk = i / (256 * 64); int rem = i - kk * 256 * 64;
        int oc = rem / 64, ic = rem - oc * 64;
        w9_2[i] = f2bf(w2[(oc * 64 + ic) * 9 + kk]);
        return;
    }
    i -= 147456;
    if (i < 589824) {
        int kk = i / 65536; int rem = i - kk * 65536;
        int oc = rem / 256, ic = rem - oc * 256;
        w9_3[i] = f2bf(wr[(oc * 256 + ic) * 9 + kk]);
    }
}

// ---------------- conv1 via MFMA: 3->64, 7x7, s4, p3, fused im2col ----------------
__global__ __launch_bounds__(256) void conv1_mfma(const float* __restrict__ img,
                                                  const unsigned short* __restrict__ wA, // [64][160]
                                                  const float* __restrict__ bias,
                                                  unsigned short* __restrict__ f1t) {
    __shared__ float sin_[3 * 7 * 260];        // input window [ic][ky][c], c=4*px+kx
    __shared__ unsigned short tileT[64 * 72];  // C transpose staging [px][oc], padded row 72
    int t = threadIdx.x;
    int wave = t >> 6, lane = t & 63;
    int quad = lane >> 4, l16 = lane & 15;
    int oy = blockIdx.y;
    int ox0 = blockIdx.x * 64;
    int gx0 = ox0 * 4 - 3;
    int gy0 = 4 * oy - 3;
    for (int idx = t; idx < 3 * 7 * 259; idx += 256) {
        int ic = idx / (7 * 259);
        int r = idx - ic * 7 * 259;
        int ky = r / 259, c = r - ky * 259;
        int gy = gy0 + ky, gx = gx0 + c;
        float v = 0.f;
        if (gy >= 0 && gy < 1600 && gx >= 0 && gx < 1600)
            v = img[(ic * 1600 + gy) * 1600 + gx];
        sin_[(ic * 7 + ky) * 260 + c] = v;
    }
    bf16x8 afr[5];
    {
        const bf16x8* ap = (const bf16x8*)(wA + (wave * 16 + l16) * 160 + quad * 8);
#pragma unroll
        for (int c = 0; c < 5; c++) afr[c] = ap[c * 4];
    }
    __syncthreads();

    f32x4 acc[4];
#pragma unroll
    for (int j = 0; j < 4; j++) acc[j] = (f32x4){0.f, 0.f, 0.f, 0.f};
    int q8 = quad * 8;
    int col4[4];
#pragma unroll
    for (int j = 0; j < 4; j++) col4[j] = 4 * (j * 16 + l16);

#pragma unroll
    for (int ch = 0; ch < 5; ch++) {
        float val[4][8];
#pragma unroll
        for (int jj = 0; jj < 8; jj++) {
            int k = ch * 32 + q8 + jj;
            int ic = (k * 335) >> 14;          // k/49 for k<160
            int r = k - ic * 49;
            int ky = (r * 37) >> 8;            // r/7 for r<49
            int kx = r - ky * 7;
            bool valid = (k < 147);
            int base = valid ? ((ic * 7 + ky) * 260 + kx) : 0;
#pragma unroll
            for (int j = 0; j < 4; j++) {
                float v = sin_[base + col4[j]];
                val[j][jj] = valid ? v : 0.f;
            }
        }
#pragma unroll
        for (int j = 0; j < 4; j++) {
            bf16x8 b;
#pragma unroll
            for (int jj = 0; jj < 8; jj++) b[jj] = (short)f2bf(val[j][jj]);
            acc[j] = __builtin_amdgcn_mfma_f32_16x16x32_bf16(afr[ch], b, acc[j], 0, 0, 0);
        }
    }
#pragma unroll
    for (int reg = 0; reg < 4; reg++) {
        int oc = wave * 16 + quad * 4 + reg;
        float bv = bias[oc];
#pragma unroll
        for (int j = 0; j < 4; j++) {
            int px = j * 16 + l16;
            tileT[px * 72 + oc] = f2bf(fmaxf(acc[j][reg] + bv, 0.f));
        }
    }
    __syncthreads();
    int px = t >> 2, part = t & 3;
    int ox = ox0 + px;
    if (ox < 400) {
        int row = (oy + 1) * 402 + ox + 1;
        uint4 v = *(const uint4*)(tileT + px * 72 + part * 16);
        *(uint4*)(f1t + row * 64 + part * 16) = v;
    }
}

// ---------------- implicit-GEMM conv via MFMA bf16 (one wave per block) ----------------
// Wave tile: 32 oc x 64 px. Grid (157, 8) = 1256 blocks of 64 threads.
// Register pipelining: A-frags for the whole pass preloaded; B double-buffered.
template<int ICC, int RS, int S, bool WRT>
__global__ __launch_bounds__(64) void conv_gemm(const unsigned short* __restrict__ Bt,
                                                const unsigned short* __restrict__ A9,
                                                const float* __restrict__ bias,
                                                float* __restrict__ outF,
                                                unsigned short* __restrict__ outT) {
    int lane = threadIdx.x;
    int quad = lane >> 4, l16 = lane & 15;
    int n0 = blockIdx.x * 64;
    int oc0 = blockIdx.y * 32;
    int y[4], x[4];
#pragma unroll
    for (int j = 0; j < 4; j++) {
        int p = n0 + j * 16 + l16;
        int pe = min(p, 9999);              // clamp: OOB lanes compute discarded garbage
        y[j] = pe / 100;
        x[j] = pe - y[j] * 100;
    }
    f32x4 acc[2][4];
#pragma unroll
    for (int a = 0; a < 2; a++)
#pragma unroll
        for (int j = 0; j < 4; j++) acc[a][j] = (f32x4){0.f, 0.f, 0.f, 0.f};

    const int KCH = ICC / 32;
    for (int pass = 0; pass < 9; pass++) {
        int ky = pass / 3, kx = pass - (pass / 3) * 3;
        const bf16x8* aP0 = (const bf16x8*)(A9 + (size_t)pass * 256 * ICC + (oc0 + l16) * ICC + quad * 8);
        const bf16x8* aP1 = (const bf16x8*)(A9 + (size_t)pass * 256 * ICC + (oc0 + 16 + l16) * ICC + quad * 8);
        // preload all A fragments of this pass (independent loads in flight)
        bf16x8 aF0[KCH], aF1[KCH];
#pragma unroll
        for (int kc = 0; kc < KCH; kc++) { aF0[kc] = aP0[kc * 4]; aF1[kc] = aP1[kc * 4]; }
        const bf16x8* bP[4];
#pragma unroll
        for (int j = 0; j < 4; j++) {
            int r = (S * y[j] + ky) * RS + S * x[j] + kx;
            bP[j] = (const bf16x8*)(Bt + (size_t)r * ICC + quad * 8);
        }
        // B double buffer
        bf16x8 bb[2][4];
#pragma unroll
        for (int j = 0; j < 4; j++) bb[0][j] = bP[j][0];
#pragma unroll
        for (int kc = 0; kc < KCH; kc++) {
            if (kc + 1 < KCH) {
#pragma unroll
                for (int j = 0; j < 4; j++) bb[(kc + 1) & 1][j] = bP[j][(kc + 1) * 4];
            }
#pragma unroll
            for (int j = 0; j < 4; j++) {
                acc[0][j] = __builtin_amdgcn_mfma_f32_16x16x32_bf16(aF0[kc], bb[kc & 1][j], acc[0][j], 0, 0, 0);
                acc[1][j] = __builtin_amdgcn_mfma_f32_16x16x32_bf16(aF1[kc], bb[kc & 1][j], acc[1][j], 0, 0, 0);
            }
        }
    }
#pragma unroll
    for (int a = 0; a < 2; a++) {
#pragma unroll
        for (int reg = 0; reg < 4; reg++) {
            int oc = oc0 + a * 16 + quad * 4 + reg;
            float bv = bias[oc];
#pragma unroll
            for (int j = 0; j < 4; j++) {
                int p = n0 + j * 16 + l16;
                if (p < 10000) {
                    float v = fmaxf(acc[a][j][reg] + bv, 0.f);
                    outF[oc * 10000 + p] = v;
                    if (WRT) {
                        int yy = p / 100, xx = p - (p / 100) * 100;
                        int r = (yy + 1) * 102 + xx + 1;
                        outT[r * 256 + oc] = f2bf(v);
                    }
                }
            }
        }
    }
}

// ---------------- 1x1 heads: partial sums over 64-channel chunks ----------------
__global__ __launch_bounds__(64) void head_kernel(const float* __restrict__ hbuf,
                                                  const float* __restrict__ wtc,  // [256][18]
                                                  const float* __restrict__ wtg,  // [256][36]
                                                  float* __restrict__ cpart,      // [4][18][10000]
                                                  float* __restrict__ rpart) {    // [4][36][10000]
    int p = blockIdx.x * 64 + threadIdx.x;
    int ch = blockIdx.y;
    int ic0 = ch * 64;
    if (p >= 10000) return;
    float acc[54];
#pragma unroll
    for (int j = 0; j < 54; j++) acc[j] = 0.f;
    for (int ic = 0; ic < 64; ic++) {
        float v = hbuf[(ic0 + ic) * 10000 + p];
        const float* wc_ = wtc + (ic0 + ic) * 18;
#pragma unroll
        for (int j = 0; j < 18; j++) acc[j] += v * wc_[j];
        const float* wg_ = wtg + (ic0 + ic) * 36;
#pragma unroll
        for (int j = 0; j < 36; j++) acc[18 + j] += v * wg_[j];
    }
    for (int j = 0; j < 18; j++) cpart[(ch * 18 + j) * 10000 + p] = acc[j];
    for (int j = 0; j < 36; j++) rpart[(ch * 36 + j) * 10000 + p] = acc[18 + j];
}

// ---------------- IoU pass 1: anc argmax + per-gt max ----------------
__global__ __launch_bounds__(256) void iou_pass1(const float* __restrict__ gt,
                                                 int* __restrict__ aarg,
                                                 unsigned int* __restrict__ gtmax) {
    __shared__ float sg[64][4];
    __shared__ float sarea[64];
    __shared__ unsigned int smax[64];
    int t = threadIdx.x;
    if (t < 64) {
#pragma clang fp contract(off)
        float b0 = gt[t * 4 + 0], b1 = gt[t * 4 + 1];
        float b2 = gt[t * 4 + 2], b3 = gt[t * 4 + 3];
        sg[t][0] = b0; sg[t][1] = b1; sg[t][2] = b2; sg[t][3] = b3;
        sarea[t] = (b2 - b0) * (b3 - b1);
        smax[t] = 0u;
    }
    __syncthreads();
    int i = blockIdx.x * 256 + t;
    int iq = min(i, 89999);              // keep all 64 lanes active for the shuffles
    float x0, y0, x1, y1, aa;
    anchor_box(iq, x0, y0, x1, y1, aa);
    float best = -1.f;
    int bestj = 0;
    for (int j = 0; j < 64; j++) {
        float v = iou_one(x0, y0, x1, y1, aa, sg[j][0], sg[j][1], sg[j][2], sg[j][3], sarea[j]);
        if (v > best) { best = v; bestj = j; }
        float vm = v;
#pragma unroll
        for (int off = 32; off > 0; off >>= 1) vm = fmaxf(vm, __shfl_xor(vm, off));
        if ((t & 63) == 0) atomicMax(&smax[j], __float_as_uint(vm));
    }
    if (i < 90000) aarg[i] = bestj;
    __syncthreads();
    if (t < 64) atomicMax(&gtmax[t], smax[t]);
}

// ---------------- IoU pass 2: labels -> ballot masks + pos compaction ----------------
__global__ __launch_bounds__(256) void iou_pass2(const float* __restrict__ gt,
                                                 const unsigned int* __restrict__ gtmax,
                                                 unsigned long long* __restrict__ negmask,
                                                 unsigned long long* __restrict__ posmask,
                                                 float* __restrict__ cand_s,
                                                 int* __restrict__ cand_i,
                                                 unsigned int* __restrict__ cnt) {
    __shared__ float sg[64][4];
    __shared__ float sarea[64];
    __shared__ float sgm[64];
    int t = threadIdx.x;
    if (t < 64) {
#pragma clang fp contract(off)
        float b0 = gt[t * 4 + 0], b1 = gt[t * 4 + 1];
        float b2 = gt[t * 4 + 2], b3 = gt[t * 4 + 3];
        sg[t][0] = b0; sg[t][1] = b1; sg[t][2] = b2; sg[t][3] = b3;
        sarea[t] = (b2 - b0) * (b3 - b1);
        sgm[t] = __uint_as_float(gtmax[t]);
    }
    __syncthreads();
    int i = blockIdx.x * 256 + t;
    if (i >= 90000) return;
    float x0, y0, x1, y1, aa;
    anchor_box(i, x0, y0, x1, y1, aa);
    float best = -1.f;
    bool isbest = false;
    for (int j = 0; j < 64; j++) {
        float v = iou_one(x0, y0, x1, y1, aa, sg[j][0], sg[j][1], sg[j][2], sg[j][3], sarea[j]);
        if (v > best) best = v;
        if (v == sgm[j]) isbest = true;   // exact equality, identical f32 code path as pass 1
    }
    float label = -1.f;
    if (best < 0.2f) label = 0.f;
    if (isbest) label = 1.f;
    if (best > 0.7f) label = 1.f;
    unsigned long long negb = __ballot(label == 0.f);
    unsigned long long posb = __ballot(label == 1.f);
    if ((t & 63) == 0) { negmask[i >> 6] = negb; posmask[i >> 6] = posb; }
    if (label == 1.f) {
        unsigned int p = atomicAdd(cnt, 1u);
        if (p < CAP) { cand_s[p] = best; cand_i[p] = i; }
    }
}

// ---------------- top-k selection on bitmasks (jax.lax.top_k semantics) ----------------
// first-32 set bits (ascending index) of a 90000-bit mask stream; 256 threads
__device__ int first32_from_mask(const unsigned long long* __restrict__ mask,
                                 bool invert, int* __restrict__ outIdx,
                                 int* scnt, int t) {
    const int NW = 1407;            // ceil(90000/64)
    const int WPT = 6;              // 256*6 = 1536 >= 1407
    unsigned long long mw[WPT];
    int cnt = 0;
#pragma unroll
    for (int u = 0; u < WPT; u++) {
        int w = t * WPT + u;
        unsigned long long m = 0ull;
        if (w < NW) {
            m = mask[w];
            if (invert) m = ~m;
            if (w == NW - 1) m &= 0xFFFFull;    // anchors 89984..89999 only
        }
        mw[u] = m;
        cnt += __builtin_popcountll(m);
    }
    scnt[t] = cnt;
    __syncthreads();
    for (int off = 1; off < 256; off <<= 1) {
        int v = (t >= off) ? scnt[t - off] : 0;
        __syncthreads();
        scnt[t] += v;
        __syncthreads();
    }
    int total = scnt[255];
    int pref = scnt[t] - cnt;       // exclusive prefix
    if (pref < 32) {
#pragma unroll
        for (int u = 0; u < WPT; u++) {
            unsigned long long m = mw[u];
            int wbase = (t * WPT + u) * 64;
            while (m && pref < 32) {
                int b = __builtin_ctzll(m);
                outIdx[pref++] = wbase + b;
                m &= m - 1;
            }
        }
    }
    __syncthreads();
    return total;
}

__global__ __launch_bounds__(256) void select_kernel(const unsigned long long* __restrict__ negmask,
                                                     const unsigned long long* __restrict__ posmask,
                                                     const float* __restrict__ cand_s,
                                                     const int* __restrict__ cand_i,
                                                     const unsigned int* __restrict__ cnt,
                                                     int* __restrict__ pidx,
                                                     int* __restrict__ nidx) {
    __shared__ float cs[CAP + 32];
    __shared__ int ci[CAP + 32];
    __shared__ int scnt[256];
    __shared__ int sfill[32];
    __shared__ float rs[256];
    __shared__ int ri[256];
    __shared__ int rslot[256];
    int t = threadIdx.x;
    int ncand = min((int)*cnt, CAP);
    for (int c = t; c < ncand; c += 256) { cs[c] = cand_s[c]; ci[c] = cand_i[c]; }
    __syncthreads();

    int nfill = 0;
    if (ncand < 32) {
        // first 32 indices with label != 1 (tie fill at value -1, index order)
        int tot = first32_from_mask(posmask, true, sfill, scnt, t);
        nfill = min(tot, 32);
        for (int k = t; k < nfill; k += 256) { cs[ncand + k] = -1.0f; ci[ncand + k] = sfill[k]; }
    }
    __syncthreads();
    int ntot = ncand + nfill;

    // 32 rounds of argmax with (score desc, index asc) comparator
    for (int s = 0; s < 32; s++) {
        float bs = -1e30f;
        int bi = 0x7fffffff;
        int bsl = -1;
        for (int c = t; c < ntot; c += 256) {
            float v = cs[c];
            int id = ci[c];
            if (v > bs || (v == bs && id < bi)) { bs = v; bi = id; bsl = c; }
        }
        rs[t] = bs; ri[t] = bi; rslot[t] = bsl;
        __syncthreads();
        for (int off = 128; off > 0; off >>= 1) {
            if (t < off) {
                if (rs[t + off] > rs[t] || (rs[t + off] == rs[t] && ri[t + off] < ri[t])) {
                    rs[t] = rs[t + off]; ri[t] = ri[t + off]; rslot[t] = rslot[t + off];
                }
            }
            __syncthreads();
        }
        if (t == 0) { pidx[s] = ri[0]; cs[rslot[0]] = -1e30f; }
        __syncthreads();
    }

    // negatives: first 32 indices with label == 0 (1e6-idx scores -> ascending index)
    int totn = first32_from_mask(negmask, false, nidx, scnt, t);
    if (t == 0) {
        int nf = min(totn, 32);
        for (int s = nf; s < 32; s++) nidx[s] = s;   // degenerate fallback
    }
}

// ---------------- finalize: proposals, losses, index outputs ----------------
__global__ __launch_bounds__(64) void finalize_kernel(const float* __restrict__ cpart,
                                                      const float* __restrict__ rpart,
                                                      const float* __restrict__ bcls,
                                                      const float* __restrict__ breg,
                                                      const int* __restrict__ pidx,
                                                      const int* __restrict__ nidx,
                                                      const int* __restrict__ aarg,
                                                      const float* __restrict__ gt,
                                                      const int* __restrict__ gtc,
                                                      float* __restrict__ out) {
#pragma clang fp contract(off)
    const int PROP_OFF = 1 + 2560000;
    int t = threadIdx.x;  // 64 threads = 1 wave
    int n = (t < 32) ? pidx[t] : nidx[t - 32];
    int a = n % 9;
    int q = n / 9;
    int iy = q % 100;
    int ix = q / 100;
    int p = iy * 100 + ix;

    float l0 = bcls[a * 2 + 0], l1 = bcls[a * 2 + 1];
    for (int c = 0; c < 4; c++) {
        l0 += cpart[(c * 18 + a * 2 + 0) * 10000 + p];
        l1 += cpart[(c * 18 + a * 2 + 1) * 10000 + p];
    }
    float m = fmaxf(l0, l1);
    float lse = m + logf(expf(l0 - m) + expf(l1 - m));
    float logp = ((t < 32) ? l1 : l0) - lse;
    float cls_sum = logp;
#pragma unroll
    for (int off = 32; off > 0; off >>= 1) cls_sum += __shfl_down(cls_sum, off);

    float reg_sum = 0.f;
    if (t < 32) {
        float offv[4];
#pragma unroll
        for (int k = 0; k < 4; k++) {
            float v = breg[a * 4 + k];
            for (int c = 0; c < 4; c++) v += rpart[(c * 36 + a * 4 + k) * 10000 + p];
            offv[k] = v;
        }
        float x0, y0, x1, y1, aa;
        anchor_box(n, x0, y0, x1, y1, aa);
        float w = x1 - x0, h = y1 - y0;
        float cx = x0 + 0.5f * w, cy = y0 + 0.5f * h;
        float ncx = cx + offv[0] * w, ncy = cy + offv[1] * h;
        float nw = w * expf(offv[2]), nh = h * expf(offv[3]);
        out[PROP_OFF + t * 4 + 0] = ncx - nw * 0.5f;
        out[PROP_OFF + t * 4 + 1] = ncy - nh * 0.5f;
        out[PROP_OFF + t * 4 + 2] = ncx + nw * 0.5f;
        out[PROP_OFF + t * 4 + 3] = ncy + nh * 0.5f;

        int j = aarg[n];
        float g0 = gt[j * 4 + 0], g1 = gt[j * 4 + 1];
        float g2 = gt[j * 4 + 2], g3 = gt[j * 4 + 3];
        float gw = g2 - g0, gh = g3 - g1;
        float gcx = g0 + 0.5f * gw, gcy = g1 + 0.5f * gh;
        float tg[4];
        tg[0] = (gcx - cx) / w;
        tg[1] = (gcy - cy) / h;
        tg[2] = logf(gw / w);
        tg[3] = logf(gh / h);
#pragma unroll
        for (int k = 0; k < 4; k++) {
            float d = tg[k] - offv[k];
            float ad = fabsf(d);
            reg_sum += (ad < 1.f) ? 0.5f * d * d : ad - 0.5f;
        }
        out[PROP_OFF + 128 + t] = (float)n;
        out[PROP_OFF + 160 + t] = (float)gtc[j];
    }
#pragma unroll
    for (int off = 32; off > 0; off >>= 1) reg_sum += __shfl_down(reg_sum, off);
    if (t == 0) {
        float cls_loss = -(cls_sum / 64.f);
        float reg_loss = reg_sum / 128.f;
        out[0] = cls_loss + 5.f * reg_loss;
    }
}

// ---------------- launch ----------------
extern "C" void kernel_launch(void* const* d_in, const int* in_sizes, int n_in,
                              void* d_out, int out_size, void* d_ws, size_t ws_size,
                              hipStream_t stream) {
    const float* img = (const float*)d_in[0];
    const float* gt  = (const float*)d_in[1];
    const int*   gtc = (const int*)d_in[2];
    const float* w1  = (const float*)d_in[3];
    const float* b1  = (const float*)d_in[4];
    const float* w2  = (const float*)d_in[5];
    const float* b2  = (const float*)d_in[6];
    const float* wr  = (const float*)d_in[7];
    const float* br  = (const float*)d_in[8];
    const float* wc  = (const float*)d_in[9];
    const float* bc  = (const float*)d_in[10];
    const float* wg  = (const float*)d_in[11];
    const float* bg  = (const float*)d_in[12];
    float* out = (float*)d_out;
    float* ws = (float*)d_ws;

    unsigned short* f1t  = (unsigned short*)(ws + OFF_F1T);
    unsigned short* fmt  = (unsigned short*)(ws + OFF_FMT);
    unsigned short* wa1  = (unsigned short*)(ws + OFF_WA1);
    unsigned short* w9_2 = (unsigned short*)(ws + OFF_W9_2);
    unsigned short* w9_3 = (unsigned short*)(ws + OFF_W9_3);
    float* hbuf  = ws + OFF_HBUF;
    float* cpart = ws + OFF_CPART;
    float* rpart = ws + OFF_RPART;
    float* wtc   = ws + OFF_WTC;
    float* wtg   = ws + OFF_WTG;
    int*   aarg  = (int*)(ws + OFF_AARG);
    unsigned long long* negm = (unsigned long long*)(ws + OFF_NEGM);
    unsigned long long* posm = (unsigned long long*)(ws + OFF_POSM);
    unsigned int* gtmax = (unsigned int*)(ws + OFF_GTMAX);
    unsigned int* cnt   = gtmax + 64;
    int*   pidx  = (int*)(ws + OFF_PIDX);
    int*   nidx  = (int*)(ws + OFF_NIDX);
    float* cands = ws + OFF_CANDS;
    int*   candi = (int*)(ws + OFF_CANDI);
    float* fm    = out + 1;   // fm lives directly in the output buffer (f32)

    setup_kernel<<<dim3(3377), dim3(256), 0, stream>>>(wc, wtc, wg, wtg, w1, wa1,
                                                       w2, w9_2, wr, w9_3,
                                                       (unsigned int*)f1t, (unsigned int*)fmt, gtmax);

    conv1_mfma<<<dim3(7, 400), dim3(256), 0, stream>>>(img, wa1, b1, f1t);
    conv_gemm<64, 402, 4, true><<<dim3(157, 8), dim3(64), 0, stream>>>(f1t, w9_2, b2, fm, fmt);
    conv_gemm<256, 102, 1, false><<<dim3(157, 8), dim3(64), 0, stream>>>(fmt, w9_3, br, hbuf, nullptr);
    head_kernel<<<dim3(157, 4), dim3(64), 0, stream>>>(hbuf, wtc, wtg, cpart, rpart);

    iou_pass1<<<dim3(352), dim3(256), 0, stream>>>(gt, aarg, gtmax);
    iou_pass2<<<dim3(352), dim3(256), 0, stream>>>(gt, gtmax, negm, posm, cands, candi, cnt);
    select_kernel<<<dim3(1), dim3(256), 0, stream>>>(negm, posm, cands, candi, cnt, pidx, nidx);
    finalize_kernel<<<dim3(1), dim3(64), 0, stream>>>(cpart, rpart, bc, bg, pidx, nidx,
                                                      aarg, gt, gtc, out);
}

// Round 6
// 358.021 us; speedup vs baseline: 3.5628x; 1.0067x over previous
//
#include <hip/hip_runtime.h>
#include <math.h>

// RegionProposalNetwork on MI355X (gfx950).
// Round 6: conv_gemm gets an XCD-aware block swizzle (each XCD owns a
// contiguous px-region across all oc-groups -> B tile resident in that XCD's
// L2, killing the 8x redundant fetch seen in round 5's counters).
// Arithmetic bit-identical to round 5.

#define CAP 4096

typedef __attribute__((ext_vector_type(8))) short bf16x8;
typedef __attribute__((ext_vector_type(4))) float f32x4;

// ---------------- workspace layout (float offsets) ----------------
#define OFF_F1T     0          // 5,171,328 f = 402*402*64 bf16 (conv1 out, padded transposed)
#define OFF_HBUF    0          // 2,560,000 f (rpn hidden; overlays F1T which is dead by then)
#define OFF_FMT     5171328    // 1,331,712 f = 102*102*256 bf16 (fm, padded transposed)
#define OFF_CPART   6503040    //   720,000 (4*18*10000)
#define OFF_RPART   7223040    // 1,440,000 (4*36*10000)
#define OFF_WA1     8663040    //     5,120 f = 64*160 bf16 (conv1 weights, K-padded)
#define OFF_W9_2    8672448    //    73,728 f = 9*256*64 bf16
#define OFF_W9_3    8746176    //   294,912 f = 9*256*256 bf16
#define OFF_WTC     9041088    //     4,608 [256][18] f32
#define OFF_WTG     9045696    //     9,216 [256][36] f32
#define OFF_AARG    9054912    //    90,000 (int)
#define OFF_NEGM    9144912    //     2,816 f = 1408 uint64 (neg label bitmask)
#define OFF_POSM    9147728    //     2,816 f = 1408 uint64 (pos label bitmask)
#define OFF_GTMAX   9150544    //    64 uint + counter (pad 80)
#define OFF_PIDX    9150624    //    32 (int)
#define OFF_NIDX    9150656    //    32 (int)
#define OFF_CANDS   9150688    //    4,096
#define OFF_CANDI   9154784    //    4,096 (int)

__device__ __forceinline__ unsigned short f2bf(float f) {   // RNE f32->bf16
    unsigned int u = __float_as_uint(f);
    u += 0x7fffu + ((u >> 16) & 1u);
    return (unsigned short)(u >> 16);
}

// ---------------- selection-path exact math ----------------
__device__ __forceinline__ void anchor_box(int i, float& x0, float& y0,
                                           float& x1, float& y1, float& area) {
#pragma clang fp contract(off)
    const float sizes[3]  = {128.f, 256.f, 512.f};
    const float ratios[3] = {0.5f, 1.f, 2.f};
    int a = i % 9;
    int q = i / 9;
    int iy = q % 100;
    int ix = q / 100;
    int s = a / 3, r = a % 3;
    float sq = sqrtf(ratios[r]);
    float w = sizes[s] * sq;
    float h = sizes[s] / sq;
    float cx = ((float)ix + 0.5f) * 16.0f;
    float cy = ((float)iy + 0.5f) * 16.0f;
    x0 = cx - w * 0.5f;
    y0 = cy - h * 0.5f;
    x1 = x0 + w;
    y1 = y0 + h;
    area = (x1 - x0) * (y1 - y0);
}

__device__ __forceinline__ float iou_one(float ax0, float ay0, float ax1, float ay1, float aa,
                                         float bx0, float by0, float bx1, float by1, float ab) {
#pragma clang fp contract(off)
    float ltx = fmaxf(ax0, bx0), lty = fmaxf(ay0, by0);
    float rbx = fminf(ax1, bx1), rby = fminf(ay1, by1);
    float iw = fmaxf(rbx - ltx, 0.0f);
    float ih = fmaxf(rby - lty, 0.0f);
    float inter = iw * ih;
    return inter / ((aa + ab) - inter);
}

// ---------------- merged setup: zero counters, pad borders, repack weights ----------------
__global__ __launch_bounds__(256) void setup_kernel(const float* __restrict__ wc, float* __restrict__ wtc,
                                                    const float* __restrict__ wg, float* __restrict__ wtg,
                                                    const float* __restrict__ w1, unsigned short* __restrict__ wa1,
                                                    const float* __restrict__ w2, unsigned short* __restrict__ w9_2,
                                                    const float* __restrict__ wr, unsigned short* __restrict__ w9_3,
                                                    unsigned int* __restrict__ f1t_u, unsigned int* __restrict__ fmt_u,
                                                    unsigned int* __restrict__ gtmax) {
    int i = blockIdx.x * 256 + threadIdx.x;
    if (i < 65) { gtmax[i] = 0u; return; }
    i -= 65;
    if (i < 103040) {   // zero pad borders of f1t / fmt
        if (i < 51328) {
            int p = i >> 5, part = i & 31;
            int x, y;
            if (p < 804) { y = (p < 402) ? 0 : 401; x = p % 402; }
            else { int j = p - 804; x = (j < 400) ? 0 : 401; y = 1 + (j % 400); }
            f1t_u[(y * 402 + x) * 32 + part] = 0u;
        } else {
            int i2 = i - 51328;
            int p = i2 >> 7, part = i2 & 127;
            int x, y;
            if (p < 204) { y = (p < 102) ? 0 : 101; x = p % 102; }
            else { int j = p - 204; x = (j < 100) ? 0 : 101; y = 1 + (j % 100); }
            fmt_u[(y * 102 + x) * 128 + part] = 0u;
        }
        return;
    }
    i -= 103040;
    if (i < 4608) { int c = i / 256, k = i - c * 256; wtc[k * 18 + c] = wc[i]; return; }
    i -= 4608;
    if (i < 9216) { int c = i / 256, k = i - c * 256; wtg[k * 36 + c] = wg[i]; return; }
    i -= 9216;
    if (i < 10240) {
        int oc = i / 160, k = i - oc * 160;
        wa1[i] = (k < 147) ? f2bf(w1[oc * 147 + k]) : (unsigned short)0;
        return;
    }
    i -= 10240;
    if (i < 147456) {
        int kk = i / (256 * 64); int rem = i - kk * 256 * 64;
        int oc = rem / 64, ic = rem - oc * 64;
        w9_2[i] = f2bf(w2[(oc * 64 + ic) * 9 + kk]);
        return;
    }
    i -= 147456;
    if (i < 589824) {
        int kk = i / 65536; int rem = i - kk * 65536;
        int oc = rem / 256, ic = rem - oc * 256;
        w9_3[i] = f2bf(wr[(oc * 256 + ic) * 9 + kk]);
    }
}

// ---------------- conv1 via MFMA: 3->64, 7x7, s4, p3, fused im2col ----------------
__global__ __launch_bounds__(256) void conv1_mfma(const float* __restrict__ img,
                                                  const unsigned short* __restrict__ wA, // [64][160]
                                                  const float* __restrict__ bias,
                                                  unsigned short* __restrict__ f1t) {
    __shared__ float sin_[3 * 7 * 260];        // input window [ic][ky][c], c=4*px+kx
    __shared__ unsigned short tileT[64 * 72];  // C transpose staging [px][oc], padded row 72
    int t = threadIdx.x;
    int wave = t >> 6, lane = t & 63;
    int quad = lane >> 4, l16 = lane & 15;
    int oy = blockIdx.y;
    int ox0 = blockIdx.x * 64;
    int gx0 = ox0 * 4 - 3;
    int gy0 = 4 * oy - 3;
    for (int idx = t; idx < 3 * 7 * 259; idx += 256) {
        int ic = idx / (7 * 259);
        int r = idx - ic * 7 * 259;
        int ky = r / 259, c = r - ky * 259;
        int gy = gy0 + ky, gx = gx0 + c;
        float v = 0.f;
        if (gy >= 0 && gy < 1600 && gx >= 0 && gx < 1600)
            v = img[(ic * 1600 + gy) * 1600 + gx];
        sin_[(ic * 7 + ky) * 260 + c] = v;
    }
    bf16x8 afr[5];
    {
        const bf16x8* ap = (const bf16x8*)(wA + (wave * 16 + l16) * 160 + quad * 8);
#pragma unroll
        for (int c = 0; c < 5; c++) afr[c] = ap[c * 4];
    }
    __syncthreads();

    f32x4 acc[4];
#pragma unroll
    for (int j = 0; j < 4; j++) acc[j] = (f32x4){0.f, 0.f, 0.f, 0.f};
    int q8 = quad * 8;
    int col4[4];
#pragma unroll
    for (int j = 0; j < 4; j++) col4[j] = 4 * (j * 16 + l16);

#pragma unroll
    for (int ch = 0; ch < 5; ch++) {
        float val[4][8];
#pragma unroll
        for (int jj = 0; jj < 8; jj++) {
            int k = ch * 32 + q8 + jj;
            int ic = (k * 335) >> 14;          // k/49 for k<160
            int r = k - ic * 49;
            int ky = (r * 37) >> 8;            // r/7 for r<49
            int kx = r - ky * 7;
            bool valid = (k < 147);
            int base = valid ? ((ic * 7 + ky) * 260 + kx) : 0;
#pragma unroll
            for (int j = 0; j < 4; j++) {
                float v = sin_[base + col4[j]];
                val[j][jj] = valid ? v : 0.f;
            }
        }
#pragma unroll
        for (int j = 0; j < 4; j++) {
            bf16x8 b;
#pragma unroll
            for (int jj = 0; jj < 8; jj++) b[jj] = (short)f2bf(val[j][jj]);
            acc[j] = __builtin_amdgcn_mfma_f32_16x16x32_bf16(afr[ch], b, acc[j], 0, 0, 0);
        }
    }
#pragma unroll
    for (int reg = 0; reg < 4; reg++) {
        int oc = wave * 16 + quad * 4 + reg;
        float bv = bias[oc];
#pragma unroll
        for (int j = 0; j < 4; j++) {
            int px = j * 16 + l16;
            tileT[px * 72 + oc] = f2bf(fmaxf(acc[j][reg] + bv, 0.f));
        }
    }
    __syncthreads();
    int px = t >> 2, part = t & 3;
    int ox = ox0 + px;
    if (ox < 400) {
        int row = (oy + 1) * 402 + ox + 1;
        uint4 v = *(const uint4*)(tileT + px * 72 + part * 16);
        *(uint4*)(f1t + row * 64 + part * 16) = v;
    }
}

// ---------------- implicit-GEMM conv via MFMA bf16 (one wave per block) ----------------
// Wave tile: 32 oc x 64 px. 1D grid of 1280 blocks, XCD-swizzled:
//   xcd = bid & 7, oc-group = (bid>>3) & 7, pg_local = bid >> 6,
//   pg = xcd*20 + pg_local  -> XCD k owns px [k*1280, k*1280+1280) for ALL oc
//   => B tile (~0.8-2.8 MB) stays resident in that XCD's 4 MB L2.
template<int ICC, int RS, int S, bool WRT>
__global__ __launch_bounds__(64) void conv_gemm(const unsigned short* __restrict__ Bt,
                                                const unsigned short* __restrict__ A9,
                                                const float* __restrict__ bias,
                                                float* __restrict__ outF,
                                                unsigned short* __restrict__ outT) {
    int bid = blockIdx.x;
    int xcd = bid & 7;
    int ocg = (bid >> 3) & 7;
    int pgl = bid >> 6;
    int pg = xcd * 20 + pgl;
    if (pg >= 157) return;
    int n0 = pg * 64;
    int oc0 = ocg * 32;
    int lane = threadIdx.x;
    int quad = lane >> 4, l16 = lane & 15;
    int y[4], x[4];
#pragma unroll
    for (int j = 0; j < 4; j++) {
        int p = n0 + j * 16 + l16;
        int pe = min(p, 9999);              // clamp: OOB lanes compute discarded garbage
        y[j] = pe / 100;
        x[j] = pe - y[j] * 100;
    }
    f32x4 acc[2][4];
#pragma unroll
    for (int a = 0; a < 2; a++)
#pragma unroll
        for (int j = 0; j < 4; j++) acc[a][j] = (f32x4){0.f, 0.f, 0.f, 0.f};

    const int KCH = ICC / 32;
    for (int pass = 0; pass < 9; pass++) {
        int ky = pass / 3, kx = pass - (pass / 3) * 3;
        const bf16x8* aP0 = (const bf16x8*)(A9 + (size_t)pass * 256 * ICC + (oc0 + l16) * ICC + quad * 8);
        const bf16x8* aP1 = (const bf16x8*)(A9 + (size_t)pass * 256 * ICC + (oc0 + 16 + l16) * ICC + quad * 8);
        // preload all A fragments of this pass (independent loads in flight)
        bf16x8 aF0[KCH], aF1[KCH];
#pragma unroll
        for (int kc = 0; kc < KCH; kc++) { aF0[kc] = aP0[kc * 4]; aF1[kc] = aP1[kc * 4]; }
        const bf16x8* bP[4];
#pragma unroll
        for (int j = 0; j < 4; j++) {
            int r = (S * y[j] + ky) * RS + S * x[j] + kx;
            bP[j] = (const bf16x8*)(Bt + (size_t)r * ICC + quad * 8);
        }
        // B double buffer
        bf16x8 bb[2][4];
#pragma unroll
        for (int j = 0; j < 4; j++) bb[0][j] = bP[j][0];
#pragma unroll
        for (int kc = 0; kc < KCH; kc++) {
            if (kc + 1 < KCH) {
#pragma unroll
                for (int j = 0; j < 4; j++) bb[(kc + 1) & 1][j] = bP[j][(kc + 1) * 4];
            }
#pragma unroll
            for (int j = 0; j < 4; j++) {
                acc[0][j] = __builtin_amdgcn_mfma_f32_16x16x32_bf16(aF0[kc], bb[kc & 1][j], acc[0][j], 0, 0, 0);
                acc[1][j] = __builtin_amdgcn_mfma_f32_16x16x32_bf16(aF1[kc], bb[kc & 1][j], acc[1][j], 0, 0, 0);
            }
        }
    }
#pragma unroll
    for (int a = 0; a < 2; a++) {
#pragma unroll
        for (int reg = 0; reg < 4; reg++) {
            int oc = oc0 + a * 16 + quad * 4 + reg;
            float bv = bias[oc];
#pragma unroll
            for (int j = 0; j < 4; j++) {
                int p = n0 + j * 16 + l16;
                if (p < 10000) {
                    float v = fmaxf(acc[a][j][reg] + bv, 0.f);
                    outF[oc * 10000 + p] = v;
                    if (WRT) {
                        int yy = p / 100, xx = p - (p / 100) * 100;
                        int r = (yy + 1) * 102 + xx + 1;
                        outT[r * 256 + oc] = f2bf(v);
                    }
                }
            }
        }
    }
}

// ---------------- 1x1 heads: partial sums over 64-channel chunks ----------------
__global__ __launch_bounds__(64) void head_kernel(const float* __restrict__ hbuf,
                                                  const float* __restrict__ wtc,  // [256][18]
                                                  const float* __restrict__ wtg,  // [256][36]
                                                  float* __restrict__ cpart,      // [4][18][10000]
                                                  float* __restrict__ rpart) {    // [4][36][10000]
    int p = blockIdx.x * 64 + threadIdx.x;
    int ch = blockIdx.y;
    int ic0 = ch * 64;
    if (p >= 10000) return;
    float acc[54];
#pragma unroll
    for (int j = 0; j < 54; j++) acc[j] = 0.f;
    for (int ic = 0; ic < 64; ic++) {
        float v = hbuf[(ic0 + ic) * 10000 + p];
        const float* wc_ = wtc + (ic0 + ic) * 18;
#pragma unroll
        for (int j = 0; j < 18; j++) acc[j] += v * wc_[j];
        const float* wg_ = wtg + (ic0 + ic) * 36;
#pragma unroll
        for (int j = 0; j < 36; j++) acc[18 + j] += v * wg_[j];
    }
    for (int j = 0; j < 18; j++) cpart[(ch * 18 + j) * 10000 + p] = acc[j];
    for (int j = 0; j < 36; j++) rpart[(ch * 36 + j) * 10000 + p] = acc[18 + j];
}

// ---------------- IoU pass 1: anc argmax + per-gt max ----------------
__global__ __launch_bounds__(256) void iou_pass1(const float* __restrict__ gt,
                                                 int* __restrict__ aarg,
                                                 unsigned int* __restrict__ gtmax) {
    __shared__ float sg[64][4];
    __shared__ float sarea[64];
    __shared__ unsigned int smax[64];
    int t = threadIdx.x;
    if (t < 64) {
#pragma clang fp contract(off)
        float b0 = gt[t * 4 + 0], b1 = gt[t * 4 + 1];
        float b2 = gt[t * 4 + 2], b3 = gt[t * 4 + 3];
        sg[t][0] = b0; sg[t][1] = b1; sg[t][2] = b2; sg[t][3] = b3;
        sarea[t] = (b2 - b0) * (b3 - b1);
        smax[t] = 0u;
    }
    __syncthreads();
    int i = blockIdx.x * 256 + t;
    int iq = min(i, 89999);              // keep all 64 lanes active for the shuffles
    float x0, y0, x1, y1, aa;
    anchor_box(iq, x0, y0, x1, y1, aa);
    float best = -1.f;
    int bestj = 0;
    for (int j = 0; j < 64; j++) {
        float v = iou_one(x0, y0, x1, y1, aa, sg[j][0], sg[j][1], sg[j][2], sg[j][3], sarea[j]);
        if (v > best) { best = v; bestj = j; }
        float vm = v;
#pragma unroll
        for (int off = 32; off > 0; off >>= 1) vm = fmaxf(vm, __shfl_xor(vm, off));
        if ((t & 63) == 0) atomicMax(&smax[j], __float_as_uint(vm));
    }
    if (i < 90000) aarg[i] = bestj;
    __syncthreads();
    if (t < 64) atomicMax(&gtmax[t], smax[t]);
}

// ---------------- IoU pass 2: labels -> ballot masks + pos compaction ----------------
__global__ __launch_bounds__(256) void iou_pass2(const float* __restrict__ gt,
                                                 const unsigned int* __restrict__ gtmax,
                                                 unsigned long long* __restrict__ negmask,
                                                 unsigned long long* __restrict__ posmask,
                                                 float* __restrict__ cand_s,
                                                 int* __restrict__ cand_i,
                                                 unsigned int* __restrict__ cnt) {
    __shared__ float sg[64][4];
    __shared__ float sarea[64];
    __shared__ float sgm[64];
    int t = threadIdx.x;
    if (t < 64) {
#pragma clang fp contract(off)
        float b0 = gt[t * 4 + 0], b1 = gt[t * 4 + 1];
        float b2 = gt[t * 4 + 2], b3 = gt[t * 4 + 3];
        sg[t][0] = b0; sg[t][1] = b1; sg[t][2] = b2; sg[t][3] = b3;
        sarea[t] = (b2 - b0) * (b3 - b1);
        sgm[t] = __uint_as_float(gtmax[t]);
    }
    __syncthreads();
    int i = blockIdx.x * 256 + t;
    if (i >= 90000) return;
    float x0, y0, x1, y1, aa;
    anchor_box(i, x0, y0, x1, y1, aa);
    float best = -1.f;
    bool isbest = false;
    for (int j = 0; j < 64; j++) {
        float v = iou_one(x0, y0, x1, y1, aa, sg[j][0], sg[j][1], sg[j][2], sg[j][3], sarea[j]);
        if (v > best) best = v;
        if (v == sgm[j]) isbest = true;   // exact equality, identical f32 code path as pass 1
    }
    float label = -1.f;
    if (best < 0.2f) label = 0.f;
    if (isbest) label = 1.f;
    if (best > 0.7f) label = 1.f;
    unsigned long long negb = __ballot(label == 0.f);
    unsigned long long posb = __ballot(label == 1.f);
    if ((t & 63) == 0) { negmask[i >> 6] = negb; posmask[i >> 6] = posb; }
    if (label == 1.f) {
        unsigned int p = atomicAdd(cnt, 1u);
        if (p < CAP) { cand_s[p] = best; cand_i[p] = i; }
    }
}

// ---------------- top-k selection on bitmasks (jax.lax.top_k semantics) ----------------
__device__ int first32_from_mask(const unsigned long long* __restrict__ mask,
                                 bool invert, int* __restrict__ outIdx,
                                 int* scnt, int t) {
    const int NW = 1407;            // ceil(90000/64)
    const int WPT = 6;              // 256*6 = 1536 >= 1407
    unsigned long long mw[WPT];
    int cnt = 0;
#pragma unroll
    for (int u = 0; u < WPT; u++) {
        int w = t * WPT + u;
        unsigned long long m = 0ull;
        if (w < NW) {
            m = mask[w];
            if (invert) m = ~m;
            if (w == NW - 1) m &= 0xFFFFull;    // anchors 89984..89999 only
        }
        mw[u] = m;
        cnt += __builtin_popcountll(m);
    }
    scnt[t] = cnt;
    __syncthreads();
    for (int off = 1; off < 256; off <<= 1) {
        int v = (t >= off) ? scnt[t - off] : 0;
        __syncthreads();
        scnt[t] += v;
        __syncthreads();
    }
    int total = scnt[255];
    int pref = scnt[t] - cnt;       // exclusive prefix
    if (pref < 32) {
#pragma unroll
        for (int u = 0; u < WPT; u++) {
            unsigned long long m = mw[u];
            int wbase = (t * WPT + u) * 64;
            while (m && pref < 32) {
                int b = __builtin_ctzll(m);
                outIdx[pref++] = wbase + b;
                m &= m - 1;
            }
        }
    }
    __syncthreads();
    return total;
}

__global__ __launch_bounds__(256) void select_kernel(const unsigned long long* __restrict__ negmask,
                                                     const unsigned long long* __restrict__ posmask,
                                                     const float* __restrict__ cand_s,
                                                     const int* __restrict__ cand_i,
                                                     const unsigned int* __restrict__ cnt,
                                                     int* __restrict__ pidx,
                                                     int* __restrict__ nidx) {
    __shared__ float cs[CAP + 32];
    __shared__ int ci[CAP + 32];
    __shared__ int scnt[256];
    __shared__ int sfill[32];
    __shared__ float rs[256];
    __shared__ int ri[256];
    __shared__ int rslot[256];
    int t = threadIdx.x;
    int ncand = min((int)*cnt, CAP);
    for (int c = t; c < ncand; c += 256) { cs[c] = cand_s[c]; ci[c] = cand_i[c]; }
    __syncthreads();

    int nfill = 0;
    if (ncand < 32) {
        int tot = first32_from_mask(posmask, true, sfill, scnt, t);
        nfill = min(tot, 32);
        for (int k = t; k < nfill; k += 256) { cs[ncand + k] = -1.0f; ci[ncand + k] = sfill[k]; }
    }
    __syncthreads();
    int ntot = ncand + nfill;

    for (int s = 0; s < 32; s++) {
        float bs = -1e30f;
        int bi = 0x7fffffff;
        int bsl = -1;
        for (int c = t; c < ntot; c += 256) {
            float v = cs[c];
            int id = ci[c];
            if (v > bs || (v == bs && id < bi)) { bs = v; bi = id; bsl = c; }
        }
        rs[t] = bs; ri[t] = bi; rslot[t] = bsl;
        __syncthreads();
        for (int off = 128; off > 0; off >>= 1) {
            if (t < off) {
                if (rs[t + off] > rs[t] || (rs[t + off] == rs[t] && ri[t + off] < ri[t])) {
                    rs[t] = rs[t + off]; ri[t] = ri[t + off]; rslot[t] = rslot[t + off];
                }
            }
            __syncthreads();
        }
        if (t == 0) { pidx[s] = ri[0]; cs[rslot[0]] = -1e30f; }
        __syncthreads();
    }

    int totn = first32_from_mask(negmask, false, nidx, scnt, t);
    if (t == 0) {
        int nf = min(totn, 32);
        for (int s = nf; s < 32; s++) nidx[s] = s;
    }
}

// ---------------- finalize: proposals, losses, index outputs ----------------
__global__ __launch_bounds__(64) void finalize_kernel(const float* __restrict__ cpart,
                                                      const float* __restrict__ rpart,
                                                      const float* __restrict__ bcls,
                                                      const float* __restrict__ breg,
                                                      const int* __restrict__ pidx,
                                                      const int* __restrict__ nidx,
                                                      const int* __restrict__ aarg,
                                                      const float* __restrict__ gt,
                                                      const int* __restrict__ gtc,
                                                      float* __restrict__ out) {
#pragma clang fp contract(off)
    const int PROP_OFF = 1 + 2560000;
    int t = threadIdx.x;  // 64 threads = 1 wave
    int n = (t < 32) ? pidx[t] : nidx[t - 32];
    int a = n % 9;
    int q = n / 9;
    int iy = q % 100;
    int ix = q / 100;
    int p = iy * 100 + ix;

    float l0 = bcls[a * 2 + 0], l1 = bcls[a * 2 + 1];
    for (int c = 0; c < 4; c++) {
        l0 += cpart[(c * 18 + a * 2 + 0) * 10000 + p];
        l1 += cpart[(c * 18 + a * 2 + 1) * 10000 + p];
    }
    float m = fmaxf(l0, l1);
    float lse = m + logf(expf(l0 - m) + expf(l1 - m));
    float logp = ((t < 32) ? l1 : l0) - lse;
    float cls_sum = logp;
#pragma unroll
    for (int off = 32; off > 0; off >>= 1) cls_sum += __shfl_down(cls_sum, off);

    float reg_sum = 0.f;
    if (t < 32) {
        float offv[4];
#pragma unroll
        for (int k = 0; k < 4; k++) {
            float v = breg[a * 4 + k];
            for (int c = 0; c < 4; c++) v += rpart[(c * 36 + a * 4 + k) * 10000 + p];
            offv[k] = v;
        }
        float x0, y0, x1, y1, aa;
        anchor_box(n, x0, y0, x1, y1, aa);
        float w = x1 - x0, h = y1 - y0;
        float cx = x0 + 0.5f * w, cy = y0 + 0.5f * h;
        float ncx = cx + offv[0] * w, ncy = cy + offv[1] * h;
        float nw = w * expf(offv[2]), nh = h * expf(offv[3]);
        out[PROP_OFF + t * 4 + 0] = ncx - nw * 0.5f;
        out[PROP_OFF + t * 4 + 1] = ncy - nh * 0.5f;
        out[PROP_OFF + t * 4 + 2] = ncx + nw * 0.5f;
        out[PROP_OFF + t * 4 + 3] = ncy + nh * 0.5f;

        int j = aarg[n];
        float g0 = gt[j * 4 + 0], g1 = gt[j * 4 + 1];
        float g2 = gt[j * 4 + 2], g3 = gt[j * 4 + 3];
        float gw = g2 - g0, gh = g3 - g1;
        float gcx = g0 + 0.5f * gw, gcy = g1 + 0.5f * gh;
        float tg[4];
        tg[0] = (gcx - cx) / w;
        tg[1] = (gcy - cy) / h;
        tg[2] = logf(gw / w);
        tg[3] = logf(gh / h);
#pragma unroll
        for (int k = 0; k < 4; k++) {
            float d = tg[k] - offv[k];
            float ad = fabsf(d);
            reg_sum += (ad < 1.f) ? 0.5f * d * d : ad - 0.5f;
        }
        out[PROP_OFF + 128 + t] = (float)n;
        out[PROP_OFF + 160 + t] = (float)gtc[j];
    }
#pragma unroll
    for (int off = 32; off > 0; off >>= 1) reg_sum += __shfl_down(reg_sum, off);
    if (t == 0) {
        float cls_loss = -(cls_sum / 64.f);
        float reg_loss = reg_sum / 128.f;
        out[0] = cls_loss + 5.f * reg_loss;
    }
}

// ---------------- launch ----------------
extern "C" void kernel_launch(void* const* d_in, const int* in_sizes, int n_in,
                              void* d_out, int out_size, void* d_ws, size_t ws_size,
                              hipStream_t stream) {
    const float* img = (const float*)d_in[0];
    const float* gt  = (const float*)d_in[1];
    const int*   gtc = (const int*)d_in[2];
    const float* w1  = (const float*)d_in[3];
    const float* b1  = (const float*)d_in[4];
    const float* w2  = (const float*)d_in[5];
    const float* b2  = (const float*)d_in[6];
    const float* wr  = (const float*)d_in[7];
    const float* br  = (const float*)d_in[8];
    const float* wc  = (const float*)d_in[9];
    const float* bc  = (const float*)d_in[10];
    const float* wg  = (const float*)d_in[11];
    const float* bg  = (const float*)d_in[12];
    float* out = (float*)d_out;
    float* ws = (float*)d_ws;

    unsigned short* f1t  = (unsigned short*)(ws + OFF_F1T);
    unsigned short* fmt  = (unsigned short*)(ws + OFF_FMT);
    unsigned short* wa1  = (unsigned short*)(ws + OFF_WA1);
    unsigned short* w9_2 = (unsigned short*)(ws + OFF_W9_2);
    unsigned short* w9_3 = (unsigned short*)(ws + OFF_W9_3);
    float* hbuf  = ws + OFF_HBUF;
    float* cpart = ws + OFF_CPART;
    float* rpart = ws + OFF_RPART;
    float* wtc   = ws + OFF_WTC;
    float* wtg   = ws + OFF_WTG;
    int*   aarg  = (int*)(ws + OFF_AARG);
    unsigned long long* negm = (unsigned long long*)(ws + OFF_NEGM);
    unsigned long long* posm = (unsigned long long*)(ws + OFF_POSM);
    unsigned int* gtmax = (unsigned int*)(ws + OFF_GTMAX);
    unsigned int* cnt   = gtmax + 64;
    int*   pidx  = (int*)(ws + OFF_PIDX);
    int*   nidx  = (int*)(ws + OFF_NIDX);
    float* cands = ws + OFF_CANDS;
    int*   candi = (int*)(ws + OFF_CANDI);
    float* fm    = out + 1;   // fm lives directly in the output buffer (f32)

    setup_kernel<<<dim3(3377), dim3(256), 0, stream>>>(wc, wtc, wg, wtg, w1, wa1,
                                                       w2, w9_2, wr, w9_3,
                                                       (unsigned int*)f1t, (unsigned int*)fmt, gtmax);

    conv1_mfma<<<dim3(7, 400), dim3(256), 0, stream>>>(img, wa1, b1, f1t);
    conv_gemm<64, 402, 4, true><<<dim3(1280), dim3(64), 0, stream>>>(f1t, w9_2, b2, fm, fmt);
    conv_gemm<256, 102, 1, false><<<dim3(1280), dim3(64), 0, stream>>>(fmt, w9_3, br, hbuf, nullptr);
    head_kernel<<<dim3(157, 4), dim3(64), 0, stream>>>(hbuf, wtc, wtg, cpart, rpart);

    iou_pass1<<<dim3(352), dim3(256), 0, stream>>>(gt, aarg, gtmax);
    iou_pass2<<<dim3(352), dim3(256), 0, stream>>>(gt, gtmax, negm, posm, cands, candi, cnt);
    select_kernel<<<dim3(1), dim3(256), 0, stream>>>(negm, posm, cands, candi, cnt, pidx, nidx);
    finalize_kernel<<<dim3(1), dim3(64), 0, stream>>>(cpart, rpart, bc, bg, pidx, nidx,
                                                      aarg, gt, gtc, out);
}